// Round 1
// baseline (1605.536 us; speedup 1.0000x reference)
//
#include <hip/hip_runtime.h>
#include <hip/hip_bf16.h>
#include <math.h>

// Problem constants (fixed by the reference)
#define B_   8
#define T_   4096
#define D_   768
#define R_   16
#define DB_  256
#define N_   (B_ * T_)      // 32768 tokens
#define NC_  64             // scan chunks per sequence
#define L_   (T_ / NC_)     // 64 steps per chunk

// GEMM tiling
#define BM 64
#define BN 64
#define BK 16

__device__ __forceinline__ float gelu_exact(float x) {
    return 0.5f * x * (1.0f + erff(x * 0.70710678118654752f));
}
__device__ __forceinline__ float sigmoidf_(float x) {
    return 1.0f / (1.0f + expf(-x));
}

// ---------------------------------------------------------------------------
// Kernel 1: H = gelu(X @ E1_w^T + E1_b)   (N x 768) @ (256 x 768)^T -> N x 256
// ---------------------------------------------------------------------------
__global__ __launch_bounds__(256)
void gemm_e1_gelu(const float* __restrict__ X, const float* __restrict__ W,
                  const float* __restrict__ bias, float* __restrict__ H) {
    __shared__ float As[BK][BM + 4];
    __shared__ float Bs[BK][BN + 4];
    const int t    = threadIdx.x;
    const int row0 = blockIdx.y * BM;   // token tile
    const int col0 = blockIdx.x * BN;   // output tile
    const int lr = t >> 2;              // loader row 0..63
    const int lk = (t & 3) * 4;         // loader k quad
    const int ty = t >> 4, tx = t & 15;
    float acc[4][4] = {};

    for (int k0 = 0; k0 < D_; k0 += BK) {
        float4 a = *(const float4*)&X[(size_t)(row0 + lr) * D_ + k0 + lk];
        float4 b = *(const float4*)&W[(size_t)(col0 + lr) * D_ + k0 + lk];
        __syncthreads();
        As[lk + 0][lr] = a.x; As[lk + 1][lr] = a.y; As[lk + 2][lr] = a.z; As[lk + 3][lr] = a.w;
        Bs[lk + 0][lr] = b.x; Bs[lk + 1][lr] = b.y; Bs[lk + 2][lr] = b.z; Bs[lk + 3][lr] = b.w;
        __syncthreads();
#pragma unroll
        for (int kk = 0; kk < BK; kk++) {
            float4 av = *(const float4*)&As[kk][ty * 4];
            float4 bv = *(const float4*)&Bs[kk][tx * 4];
            float aa[4] = {av.x, av.y, av.z, av.w};
            float bb[4] = {bv.x, bv.y, bv.z, bv.w};
#pragma unroll
            for (int i = 0; i < 4; i++)
#pragma unroll
                for (int j = 0; j < 4; j++)
                    acc[i][j] = fmaf(aa[i], bb[j], acc[i][j]);
        }
    }
#pragma unroll
    for (int i = 0; i < 4; i++) {
        int r = row0 + ty * 4 + i;
        float4 o;
        float* po = (float*)&o;
#pragma unroll
        for (int j = 0; j < 4; j++) {
            int c = col0 + tx * 4 + j;
            po[j] = gelu_exact(acc[i][j] + bias[c]);
        }
        *(float4*)&H[(size_t)r * DB_ + col0 + tx * 4] = o;
    }
}

// ---------------------------------------------------------------------------
// Kernel 2 (per token): Z = x@V^T, alpha = sigmoid(h@E2^T+b), Bu = Z@U^T,
//                       lam = sigmoid(a_base + alpha_rep * tanh(a_delta))
// One block (256 threads) per token.
// ---------------------------------------------------------------------------
__global__ __launch_bounds__(256)
void token_small(const float* __restrict__ X, const float* __restrict__ H,
                 const float* __restrict__ Vw, const float* __restrict__ Uw,
                 const float* __restrict__ E2w, const float* __restrict__ E2b,
                 const float* __restrict__ a_base, const float* __restrict__ a_delta,
                 float* __restrict__ Lam, float* __restrict__ Bu) {
    __shared__ float xs[D_];
    __shared__ float Zs[R_];
    __shared__ float alphas[3];
    __shared__ float red[3][4];
    const int t = threadIdx.x;
    const size_t tok = blockIdx.x;
    const float* xrow = X + tok * D_;
#pragma unroll
    for (int i = 0; i < 3; i++) xs[t + 256 * i] = xrow[t + 256 * i];
    __syncthreads();

    // Z[g], g = t>>4: 16 groups of 16 lanes; lanes of a group stay in one wave.
    {
        const int g = t >> 4;
        const int j = t & 15;
        const float* vrow = Vw + g * D_;
        float z = 0.f;
        for (int i = j; i < D_; i += 16) z = fmaf(xs[i], vrow[i], z);
        z += __shfl_xor(z, 1); z += __shfl_xor(z, 2);
        z += __shfl_xor(z, 4); z += __shfl_xor(z, 8);
        if (j == 0) Zs[g] = z;
    }
    // alpha partial products (h row is exactly 256 wide = blockDim)
    {
        float hv = H[tok * DB_ + t];
        float p0 = hv * E2w[0 * DB_ + t];
        float p1 = hv * E2w[1 * DB_ + t];
        float p2 = hv * E2w[2 * DB_ + t];
#pragma unroll
        for (int m = 32; m >= 1; m >>= 1) {
            p0 += __shfl_xor(p0, m);
            p1 += __shfl_xor(p1, m);
            p2 += __shfl_xor(p2, m);
        }
        int lane = t & 63, wave = t >> 6;
        if (lane == 0) { red[0][wave] = p0; red[1][wave] = p1; red[2][wave] = p2; }
    }
    __syncthreads();
    if (t < 3) {
        float s = red[t][0] + red[t][1] + red[t][2] + red[t][3];
        alphas[t] = sigmoidf_(s + E2b[t]);
    }
    __syncthreads();

    // Bu + lam: 3 channels per thread; bucket boundary == 256 == chunk stride
#pragma unroll
    for (int ch = 0; ch < 3; ch++) {
        int d = t + 256 * ch;
        const float4* u4 = (const float4*)(Uw + (size_t)d * R_);
        float4 u0 = u4[0], u1 = u4[1], u2 = u4[2], u3 = u4[3];
        float bu = Zs[0]  * u0.x + Zs[1]  * u0.y + Zs[2]  * u0.z + Zs[3]  * u0.w
                 + Zs[4]  * u1.x + Zs[5]  * u1.y + Zs[6]  * u1.z + Zs[7]  * u1.w
                 + Zs[8]  * u2.x + Zs[9]  * u2.y + Zs[10] * u2.z + Zs[11] * u2.w
                 + Zs[12] * u3.x + Zs[13] * u3.y + Zs[14] * u3.z + Zs[15] * u3.w;
        float a_eff = a_base[d] + alphas[ch] * tanhf(a_delta[d]);
        size_t o = tok * D_ + d;
        Bu[o]  = bu;
        Lam[o] = sigmoidf_(a_eff);   // exp(-softplus(-a)) == sigmoid(a)
    }
}

// ---------------------------------------------------------------------------
// Chunked parallel scan over T:  s_t = lam_t * s_{t-1} + bu_t
// pass1: per-chunk aggregates (A = prod lam, Send = local scan end)
// pass2: scan aggregates across chunks -> carry-in per chunk
// pass3: redo local scan with carry-in, write S (in place over Bu)
// ---------------------------------------------------------------------------
__global__ void scan_pass1(const float* __restrict__ lam, const float* __restrict__ bu,
                           float* __restrict__ Aagg, float* __restrict__ Send) {
    const int d = threadIdx.x;          // 768 threads
    const int c = blockIdx.x % NC_;
    const int b = blockIdx.x / NC_;
    const size_t base = ((size_t)(b * T_ + c * L_)) * D_ + d;
    float a = 1.f, s = 0.f;
    for (int i = 0; i < L_; i++) {
        float l = lam[base + (size_t)i * D_];
        float u = bu[base + (size_t)i * D_];
        a *= l;
        s = fmaf(l, s, u);
    }
    size_t o = ((size_t)(b * NC_ + c)) * D_ + d;
    Aagg[o] = a;
    Send[o] = s;
}

__global__ void scan_pass2(const float* __restrict__ Aagg, const float* __restrict__ Send,
                           float* __restrict__ Cin) {
    const int d = threadIdx.x;          // 768 threads
    const int b = blockIdx.x;           // 8 blocks
    float s = 0.f;
    for (int c = 0; c < NC_; c++) {
        size_t o = ((size_t)(b * NC_ + c)) * D_ + d;
        Cin[o] = s;
        s = fmaf(Aagg[o], s, Send[o]);
    }
}

__global__ void scan_pass3(const float* __restrict__ lam, const float* __restrict__ Cin,
                           float* __restrict__ BuS) {   // reads Bu, writes S in place
    const int d = threadIdx.x;
    const int c = blockIdx.x % NC_;
    const int b = blockIdx.x / NC_;
    const size_t base = ((size_t)(b * T_ + c * L_)) * D_ + d;
    float s = Cin[((size_t)(b * NC_ + c)) * D_ + d];
    for (int i = 0; i < L_; i++) {
        size_t o = base + (size_t)i * D_;
        float l = lam[o];
        float u = BuS[o];
        s = fmaf(l, s, u);
        BuS[o] = s;
    }
}

// ---------------------------------------------------------------------------
// Kernel 6: out = x + gelu(S @ C^T) * sigmoid(x @ G^T + G_b)
// Dual GEMM: both D x D matmuls share the k-loop in one block.
// ---------------------------------------------------------------------------
__global__ __launch_bounds__(256)
void dual_gemm_out(const float* __restrict__ S, const float* __restrict__ X,
                   const float* __restrict__ Cw, const float* __restrict__ Gw,
                   const float* __restrict__ Gb, float* __restrict__ out) {
    __shared__ float As1[BK][BM + 4], As2[BK][BM + 4];
    __shared__ float Bs1[BK][BN + 4], Bs2[BK][BN + 4];
    const int t    = threadIdx.x;
    const int row0 = blockIdx.y * BM;
    const int col0 = blockIdx.x * BN;
    const int lr = t >> 2;
    const int lk = (t & 3) * 4;
    const int ty = t >> 4, tx = t & 15;
    float acc1[4][4] = {}, acc2[4][4] = {};

    for (int k0 = 0; k0 < D_; k0 += BK) {
        float4 a1 = *(const float4*)&S [(size_t)(row0 + lr) * D_ + k0 + lk];
        float4 a2 = *(const float4*)&X [(size_t)(row0 + lr) * D_ + k0 + lk];
        float4 b1 = *(const float4*)&Cw[(size_t)(col0 + lr) * D_ + k0 + lk];
        float4 b2 = *(const float4*)&Gw[(size_t)(col0 + lr) * D_ + k0 + lk];
        __syncthreads();
        As1[lk + 0][lr] = a1.x; As1[lk + 1][lr] = a1.y; As1[lk + 2][lr] = a1.z; As1[lk + 3][lr] = a1.w;
        As2[lk + 0][lr] = a2.x; As2[lk + 1][lr] = a2.y; As2[lk + 2][lr] = a2.z; As2[lk + 3][lr] = a2.w;
        Bs1[lk + 0][lr] = b1.x; Bs1[lk + 1][lr] = b1.y; Bs1[lk + 2][lr] = b1.z; Bs1[lk + 3][lr] = b1.w;
        Bs2[lk + 0][lr] = b2.x; Bs2[lk + 1][lr] = b2.y; Bs2[lk + 2][lr] = b2.z; Bs2[lk + 3][lr] = b2.w;
        __syncthreads();
#pragma unroll
        for (int kk = 0; kk < BK; kk++) {
            float4 av1 = *(const float4*)&As1[kk][ty * 4];
            float4 av2 = *(const float4*)&As2[kk][ty * 4];
            float4 bv1 = *(const float4*)&Bs1[kk][tx * 4];
            float4 bv2 = *(const float4*)&Bs2[kk][tx * 4];
            float aa1[4] = {av1.x, av1.y, av1.z, av1.w};
            float aa2[4] = {av2.x, av2.y, av2.z, av2.w};
            float bb1[4] = {bv1.x, bv1.y, bv1.z, bv1.w};
            float bb2[4] = {bv2.x, bv2.y, bv2.z, bv2.w};
#pragma unroll
            for (int i = 0; i < 4; i++)
#pragma unroll
                for (int j = 0; j < 4; j++) {
                    acc1[i][j] = fmaf(aa1[i], bb1[j], acc1[i][j]);
                    acc2[i][j] = fmaf(aa2[i], bb2[j], acc2[i][j]);
                }
        }
    }
    // epilogue: out = x + gelu(y) * sigmoid(g + Gb)
#pragma unroll
    for (int i = 0; i < 4; i++) {
        int r = row0 + ty * 4 + i;
        float4 xr = *(const float4*)&X[(size_t)r * D_ + col0 + tx * 4];
        float4 gb = *(const float4*)&Gb[col0 + tx * 4];
        float xx[4] = {xr.x, xr.y, xr.z, xr.w};
        float bb[4] = {gb.x, gb.y, gb.z, gb.w};
        float4 o;
        float* po = (float*)&o;
#pragma unroll
        for (int j = 0; j < 4; j++) {
            float y = gelu_exact(acc1[i][j]);
            float g = sigmoidf_(acc2[i][j] + bb[j]);
            po[j] = xx[j] + y * g;
        }
        *(float4*)&out[(size_t)r * D_ + col0 + tx * 4] = o;
    }
}

// ---------------------------------------------------------------------------
extern "C" void kernel_launch(void* const* d_in, const int* in_sizes, int n_in,
                              void* d_out, int out_size, void* d_ws, size_t ws_size,
                              hipStream_t stream) {
    const float* x       = (const float*)d_in[0];
    const float* V_w     = (const float*)d_in[1];
    const float* U_w     = (const float*)d_in[2];
    const float* E1_w    = (const float*)d_in[3];
    const float* E1_b    = (const float*)d_in[4];
    const float* E2_w    = (const float*)d_in[5];
    const float* E2_b    = (const float*)d_in[6];
    const float* a_base  = (const float*)d_in[7];
    const float* a_delta = (const float*)d_in[8];
    const float* C_w     = (const float*)d_in[9];
    const float* G_w     = (const float*)d_in[10];
    const float* G_b     = (const float*)d_in[11];
    float* out = (float*)d_out;

    // workspace layout (floats): H | Lam | Bu/S | Aagg | Send | Cin  (~229 MiB)
    float* ws   = (float*)d_ws;
    float* H    = ws;                                  // N*DB
    float* Lam  = H    + (size_t)N_ * DB_;             // N*D
    float* Bu   = Lam  + (size_t)N_ * D_;              // N*D (becomes S in place)
    float* Aagg = Bu   + (size_t)N_ * D_;              // B*NC*D
    float* Send = Aagg + (size_t)B_ * NC_ * D_;
    float* Cin  = Send + (size_t)B_ * NC_ * D_;

    dim3 g1(DB_ / BN, N_ / BM);   // (4, 512): n-tile fastest for A-tile L2 reuse
    gemm_e1_gelu<<<g1, 256, 0, stream>>>(x, E1_w, E1_b, H);

    token_small<<<N_, 256, 0, stream>>>(x, H, V_w, U_w, E2_w, E2_b,
                                        a_base, a_delta, Lam, Bu);

    scan_pass1<<<B_ * NC_, D_, 0, stream>>>(Lam, Bu, Aagg, Send);
    scan_pass2<<<B_,       D_, 0, stream>>>(Aagg, Send, Cin);
    scan_pass3<<<B_ * NC_, D_, 0, stream>>>(Lam, Cin, Bu);

    dim3 g2(D_ / BN, N_ / BM);    // (12, 512)
    dual_gemm_out<<<g2, 256, 0, stream>>>(Bu, x, C_w, G_w, G_b, out);
}

// Round 2
// 692.487 us; speedup vs baseline: 2.3185x; 2.3185x over previous
//
#include <hip/hip_runtime.h>
#include <hip/hip_bf16.h>
#include <math.h>

// Problem constants
#define B_   8
#define T_   4096
#define D_   768
#define R_   16
#define DB_  256
#define N_   (B_ * T_)      // 32768 tokens
#define NC_  64             // scan chunks per sequence
#define L_   (T_ / NC_)     // 64 steps per chunk

typedef __attribute__((ext_vector_type(8))) short bf16x8;
typedef __attribute__((ext_vector_type(4))) float f32x4;

__device__ __forceinline__ float gelu_exact(float x) {
    return 0.5f * x * (1.0f + erff(x * 0.70710678118654752f));
}
__device__ __forceinline__ float sigmoidf_(float x) {
    return 1.0f / (1.0f + expf(-x));
}
__device__ __forceinline__ float bf2f(unsigned short u) {
    return __uint_as_float(((unsigned)u) << 16);
}
__device__ __forceinline__ unsigned short f2bf(float f) {
    __hip_bfloat16 h = __float2bfloat16(f);   // RNE
    return *(unsigned short*)&h;
}

// async global->LDS, 16B per lane. LDS dest = wave-uniform base + lane*16.
__device__ __forceinline__ void gload16(const unsigned short* g, unsigned short* l) {
    __builtin_amdgcn_global_load_lds(
        (const __attribute__((address_space(1))) unsigned int*)(const void*)g,
        (__attribute__((address_space(3))) unsigned int*)(void*)l,
        16, 0, 0);
}

// ---------------------------------------------------------------------------
// Stage a 128x32 bf16 tile (rows row0.., k0..k0+32) from row-major src (ld=K
// elements) into LDS. LDS slot (row,q16) holds global quad q16^((row>>1)&3)
// so the swizzled frag_read below is bank-conflict-free (rule 21: permute the
// SOURCE, keep LDS dest linear for global_load_lds).
// ---------------------------------------------------------------------------
__device__ __forceinline__ void stage_tile(const unsigned short* src, int ld,
                                           int row0, int k0,
                                           unsigned short* lds, int w, int l) {
#pragma unroll
    for (int j = 0; j < 2; ++j) {
        int i   = ((w * 2 + j) << 6) + l;   // 0..511 16B-chunks
        int row = i >> 2;
        int q   = i & 3;
        int qs  = q ^ ((row >> 1) & 3);
        const unsigned short* g = src + (size_t)(row0 + row) * ld + k0 + qs * 8;
        gload16(g, lds + ((w * 2 + j) << 9));   // 1024B per wave-issue
    }
}

// swizzled LDS fragment read: 8 bf16 for mfma_16x16x32 (row = M-or-N index)
__device__ __forceinline__ bf16x8 frag_read(const unsigned short* lds, int row, int lq) {
    int q = lq ^ ((row >> 1) & 3);
    return *(const bf16x8*)(lds + row * 32 + q * 8);
}

// ---------------------------------------------------------------------------
// Kernel: H = gelu(Xb @ E1^T + b) -> bf16   (N x 768)(256 x 768)^T = N x 256
// 128x128 tile, 4 waves, 4x4 16x16 fragments/wave, BK=32
// ---------------------------------------------------------------------------
__global__ __launch_bounds__(256)
void gemm_e1_mfma(const unsigned short* __restrict__ Xb,
                  const unsigned short* __restrict__ Wb,
                  const float* __restrict__ bias,
                  unsigned short* __restrict__ H) {
    __shared__ unsigned short ldsA[128 * 32], ldsB[128 * 32];
    const int t = threadIdx.x, l = t & 63, w = t >> 6;
    const int row0 = blockIdx.y * 128, col0 = blockIdx.x * 128;
    const int wrow = (w >> 1) * 64, wcol = (w & 1) * 64;
    const int lr = l & 15, lq = l >> 4;
    f32x4 acc[4][4] = {};

    for (int k0 = 0; k0 < D_; k0 += 32) {
        stage_tile(Xb, D_, row0, k0, ldsA, w, l);
        stage_tile(Wb, D_, col0, k0, ldsB, w, l);
        __syncthreads();
        bf16x8 a[4], b[4];
#pragma unroll
        for (int m = 0; m < 4; m++) a[m] = frag_read(ldsA, wrow + m * 16 + lr, lq);
#pragma unroll
        for (int n = 0; n < 4; n++) b[n] = frag_read(ldsB, wcol + n * 16 + lr, lq);
#pragma unroll
        for (int m = 0; m < 4; m++)
#pragma unroll
            for (int n = 0; n < 4; n++)
                acc[m][n] = __builtin_amdgcn_mfma_f32_16x16x32_bf16(a[m], b[n], acc[m][n], 0, 0, 0);
        __syncthreads();
    }
    // C/D layout: col = lane&15, row = (lane>>4)*4 + reg
#pragma unroll
    for (int m = 0; m < 4; m++)
#pragma unroll
        for (int n = 0; n < 4; n++) {
            int col = col0 + wcol + n * 16 + lr;
            float bc = bias[col];
#pragma unroll
            for (int r = 0; r < 4; r++) {
                int row = row0 + wrow + m * 16 + lq * 4 + r;
                H[(size_t)row * DB_ + col] = f2bf(gelu_exact(acc[m][n][r] + bc));
            }
        }
}

// ---------------------------------------------------------------------------
// Dual GEMM + epilogue: out = x + gelu(S@C^T) * sigmoid(x@G^T + Gb)
// ---------------------------------------------------------------------------
__global__ __launch_bounds__(256)
void dual_gemm_mfma(const unsigned short* __restrict__ Sb,
                    const unsigned short* __restrict__ Xb,
                    const unsigned short* __restrict__ Cwb,
                    const unsigned short* __restrict__ Gwb,
                    const float* __restrict__ X32,
                    const float* __restrict__ Gbias,
                    float* __restrict__ out) {
    __shared__ unsigned short ldsA1[128 * 32], ldsA2[128 * 32];
    __shared__ unsigned short ldsB1[128 * 32], ldsB2[128 * 32];
    const int t = threadIdx.x, l = t & 63, w = t >> 6;
    const int row0 = blockIdx.y * 128, col0 = blockIdx.x * 128;
    const int wrow = (w >> 1) * 64, wcol = (w & 1) * 64;
    const int lr = l & 15, lq = l >> 4;
    f32x4 acc1[4][4] = {}, acc2[4][4] = {};

    for (int k0 = 0; k0 < D_; k0 += 32) {
        stage_tile(Sb,  D_, row0, k0, ldsA1, w, l);
        stage_tile(Xb,  D_, row0, k0, ldsA2, w, l);
        stage_tile(Cwb, D_, col0, k0, ldsB1, w, l);
        stage_tile(Gwb, D_, col0, k0, ldsB2, w, l);
        __syncthreads();
        bf16x8 a[4], b[4];
#pragma unroll
        for (int m = 0; m < 4; m++) a[m] = frag_read(ldsA1, wrow + m * 16 + lr, lq);
#pragma unroll
        for (int n = 0; n < 4; n++) b[n] = frag_read(ldsB1, wcol + n * 16 + lr, lq);
#pragma unroll
        for (int m = 0; m < 4; m++)
#pragma unroll
            for (int n = 0; n < 4; n++)
                acc1[m][n] = __builtin_amdgcn_mfma_f32_16x16x32_bf16(a[m], b[n], acc1[m][n], 0, 0, 0);
#pragma unroll
        for (int m = 0; m < 4; m++) a[m] = frag_read(ldsA2, wrow + m * 16 + lr, lq);
#pragma unroll
        for (int n = 0; n < 4; n++) b[n] = frag_read(ldsB2, wcol + n * 16 + lr, lq);
#pragma unroll
        for (int m = 0; m < 4; m++)
#pragma unroll
            for (int n = 0; n < 4; n++)
                acc2[m][n] = __builtin_amdgcn_mfma_f32_16x16x32_bf16(a[m], b[n], acc2[m][n], 0, 0, 0);
        __syncthreads();
    }
#pragma unroll
    for (int m = 0; m < 4; m++)
#pragma unroll
        for (int n = 0; n < 4; n++) {
            int col = col0 + wcol + n * 16 + lr;
            float gb = Gbias[col];
#pragma unroll
            for (int r = 0; r < 4; r++) {
                int row = row0 + wrow + m * 16 + lq * 4 + r;
                size_t o = (size_t)row * D_ + col;
                float y = gelu_exact(acc1[m][n][r]);
                float g = sigmoidf_(acc2[m][n][r] + gb);
                out[o] = X32[o] + y * g;
            }
        }
}

// ---------------------------------------------------------------------------
// Per token: Z = x@V^T, alpha = sigmoid(h@E2^T+b), Bu = Z@U^T,
//            lam = sigmoid(a_base + alpha_rep * tanh(a_delta))
// ---------------------------------------------------------------------------
__global__ __launch_bounds__(256)
void token_small(const unsigned short* __restrict__ Xb, const unsigned short* __restrict__ H,
                 const float* __restrict__ Vw, const float* __restrict__ Uw,
                 const float* __restrict__ E2w, const float* __restrict__ E2b,
                 const float* __restrict__ a_base, const float* __restrict__ tanhd,
                 unsigned short* __restrict__ Lam, unsigned short* __restrict__ Bu) {
    __shared__ float xs[D_];
    __shared__ float Zs[R_];
    __shared__ float alphas[3];
    __shared__ float red[3][4];
    const int t = threadIdx.x;
    const size_t tok = blockIdx.x;
    if (t < 192) {
        ushort4 v = *(const ushort4*)&Xb[tok * D_ + t * 4];
        xs[t * 4 + 0] = bf2f(v.x); xs[t * 4 + 1] = bf2f(v.y);
        xs[t * 4 + 2] = bf2f(v.z); xs[t * 4 + 3] = bf2f(v.w);
    }
    __syncthreads();

    {   // Z[g]: 16 groups of 16 lanes (lanes of a group stay in one wave)
        const int g = t >> 4, j = t & 15;
        const float* vrow = Vw + g * D_;
        float z = 0.f;
        for (int i = j; i < D_; i += 16) z = fmaf(xs[i], vrow[i], z);
        z += __shfl_xor(z, 1); z += __shfl_xor(z, 2);
        z += __shfl_xor(z, 4); z += __shfl_xor(z, 8);
        if (j == 0) Zs[g] = z;
    }
    {   // alpha partials (h row is exactly 256 = blockDim)
        float hv = bf2f(H[tok * DB_ + t]);
        float p0 = hv * E2w[0 * DB_ + t];
        float p1 = hv * E2w[1 * DB_ + t];
        float p2 = hv * E2w[2 * DB_ + t];
#pragma unroll
        for (int m = 32; m >= 1; m >>= 1) {
            p0 += __shfl_xor(p0, m);
            p1 += __shfl_xor(p1, m);
            p2 += __shfl_xor(p2, m);
        }
        int lane = t & 63, wave = t >> 6;
        if (lane == 0) { red[0][wave] = p0; red[1][wave] = p1; red[2][wave] = p2; }
    }
    __syncthreads();
    if (t < 3) {
        float s = red[t][0] + red[t][1] + red[t][2] + red[t][3];
        alphas[t] = sigmoidf_(s + E2b[t]);
    }
    __syncthreads();

#pragma unroll
    for (int ch = 0; ch < 3; ch++) {
        int d = t + 256 * ch;
        const float4* u4 = (const float4*)(Uw + (size_t)d * R_);
        float4 u0 = u4[0], u1 = u4[1], u2 = u4[2], u3 = u4[3];
        float bu = Zs[0]  * u0.x + Zs[1]  * u0.y + Zs[2]  * u0.z + Zs[3]  * u0.w
                 + Zs[4]  * u1.x + Zs[5]  * u1.y + Zs[6]  * u1.z + Zs[7]  * u1.w
                 + Zs[8]  * u2.x + Zs[9]  * u2.y + Zs[10] * u2.z + Zs[11] * u2.w
                 + Zs[12] * u3.x + Zs[13] * u3.y + Zs[14] * u3.z + Zs[15] * u3.w;
        float a_eff = a_base[d] + alphas[ch] * tanhd[d];
        size_t o = tok * D_ + d;
        Bu[o]  = f2bf(bu);
        Lam[o] = f2bf(sigmoidf_(a_eff));   // exp(-softplus(-a)) == sigmoid(a)
    }
}

// ---------------------------------------------------------------------------
// Chunked parallel scan: s_t = lam_t * s_{t-1} + bu_t    (bf16 in, fp32 state)
// 192 threads x 4 channels
// ---------------------------------------------------------------------------
__global__ void scan_pass1(const unsigned short* __restrict__ lam,
                           const unsigned short* __restrict__ bu,
                           float* __restrict__ Aagg, float* __restrict__ Send) {
    const int th = threadIdx.x;             // 0..191
    const int c = blockIdx.x & (NC_ - 1);
    const int b = blockIdx.x >> 6;
    const size_t base = ((size_t)(b * T_ + c * L_)) * D_ + th * 4;
    float a[4] = {1.f, 1.f, 1.f, 1.f}, s[4] = {};
    for (int i = 0; i < L_; i++) {
        ushort4 lv = *(const ushort4*)&lam[base + (size_t)i * D_];
        ushort4 uv = *(const ushort4*)&bu [base + (size_t)i * D_];
        float lf[4] = {bf2f(lv.x), bf2f(lv.y), bf2f(lv.z), bf2f(lv.w)};
        float uf[4] = {bf2f(uv.x), bf2f(uv.y), bf2f(uv.z), bf2f(uv.w)};
#pragma unroll
        for (int j = 0; j < 4; j++) { a[j] *= lf[j]; s[j] = fmaf(lf[j], s[j], uf[j]); }
    }
    size_t o = ((size_t)(b * NC_ + c)) * D_ + th * 4;
#pragma unroll
    for (int j = 0; j < 4; j++) { Aagg[o + j] = a[j]; Send[o + j] = s[j]; }
}

__global__ void scan_pass2(const float* __restrict__ Aagg, const float* __restrict__ Send,
                           float* __restrict__ Cin) {
    const int d = threadIdx.x;              // 768 threads
    const int b = blockIdx.x;               // 8 blocks
    float s = 0.f;
    for (int c = 0; c < NC_; c++) {
        size_t o = ((size_t)(b * NC_ + c)) * D_ + d;
        Cin[o] = s;
        s = fmaf(Aagg[o], s, Send[o]);
    }
}

__global__ void scan_pass3(const unsigned short* __restrict__ lam,
                           const unsigned short* __restrict__ bu,
                           const float* __restrict__ Cin,
                           unsigned short* __restrict__ Sout) {   // bf16 S
    const int th = threadIdx.x;
    const int c = blockIdx.x & (NC_ - 1);
    const int b = blockIdx.x >> 6;
    const size_t base = ((size_t)(b * T_ + c * L_)) * D_ + th * 4;
    size_t ci = ((size_t)(b * NC_ + c)) * D_ + th * 4;
    float s[4] = {Cin[ci], Cin[ci + 1], Cin[ci + 2], Cin[ci + 3]};
    for (int i = 0; i < L_; i++) {
        size_t o = base + (size_t)i * D_;
        ushort4 lv = *(const ushort4*)&lam[o];
        ushort4 uv = *(const ushort4*)&bu[o];
        float lf[4] = {bf2f(lv.x), bf2f(lv.y), bf2f(lv.z), bf2f(lv.w)};
        float uf[4] = {bf2f(uv.x), bf2f(uv.y), bf2f(uv.z), bf2f(uv.w)};
#pragma unroll
        for (int j = 0; j < 4; j++) s[j] = fmaf(lf[j], s[j], uf[j]);
        ushort4 ov = make_ushort4(f2bf(s[0]), f2bf(s[1]), f2bf(s[2]), f2bf(s[3]));
        *(ushort4*)&Sout[o] = ov;
    }
}

// ---------------------------------------------------------------------------
// small conversion kernels
// ---------------------------------------------------------------------------
__global__ void cvt_bf16_vec(const float* __restrict__ in, unsigned short* __restrict__ out, int n4) {
    int i = blockIdx.x * 256 + threadIdx.x;
    if (i < n4) {
        float4 v = ((const float4*)in)[i];
        ((ushort4*)out)[i] = make_ushort4(f2bf(v.x), f2bf(v.y), f2bf(v.z), f2bf(v.w));
    }
}
__global__ void tanh_vec(const float* __restrict__ in, float* __restrict__ out, int n) {
    int i = blockIdx.x * 256 + threadIdx.x;
    if (i < n) out[i] = tanhf(in[i]);
}

// ---------------------------------------------------------------------------
extern "C" void kernel_launch(void* const* d_in, const int* in_sizes, int n_in,
                              void* d_out, int out_size, void* d_ws, size_t ws_size,
                              hipStream_t stream) {
    const float* x       = (const float*)d_in[0];
    const float* V_w     = (const float*)d_in[1];
    const float* U_w     = (const float*)d_in[2];
    const float* E1_w    = (const float*)d_in[3];
    const float* E1_b    = (const float*)d_in[4];
    const float* E2_w    = (const float*)d_in[5];
    const float* E2_b    = (const float*)d_in[6];
    const float* a_base  = (const float*)d_in[7];
    const float* a_delta = (const float*)d_in[8];
    const float* C_w     = (const float*)d_in[9];
    const float* G_w     = (const float*)d_in[10];
    const float* G_b     = (const float*)d_in[11];
    float* out = (float*)d_out;

    // workspace layout
    char* p = (char*)d_ws;
    float* Aagg  = (float*)p;           p += (size_t)B_ * NC_ * D_ * 4;
    float* Send  = (float*)p;           p += (size_t)B_ * NC_ * D_ * 4;
    float* Cin   = (float*)p;           p += (size_t)B_ * NC_ * D_ * 4;
    float* tanhd = (float*)p;           p += (size_t)D_ * 4;
    unsigned short* x_bf  = (unsigned short*)p; p += (size_t)N_ * D_ * 2;
    unsigned short* H_bf  = (unsigned short*)p; p += (size_t)N_ * DB_ * 2;
    unsigned short* Lam   = (unsigned short*)p; p += (size_t)N_ * D_ * 2;
    unsigned short* Bu    = (unsigned short*)p; p += (size_t)N_ * D_ * 2;
    unsigned short* S_bf  = (unsigned short*)p; p += (size_t)N_ * D_ * 2;
    unsigned short* E1_bf = (unsigned short*)p; p += (size_t)DB_ * D_ * 2;
    unsigned short* Cw_bf = (unsigned short*)p; p += (size_t)D_ * D_ * 2;
    unsigned short* Gw_bf = (unsigned short*)p; p += (size_t)D_ * D_ * 2;

    // conversions
    {
        int n4 = N_ * D_ / 4;
        cvt_bf16_vec<<<(n4 + 255) / 256, 256, 0, stream>>>(x, x_bf, n4);
        n4 = DB_ * D_ / 4;
        cvt_bf16_vec<<<(n4 + 255) / 256, 256, 0, stream>>>(E1_w, E1_bf, n4);
        n4 = D_ * D_ / 4;
        cvt_bf16_vec<<<(n4 + 255) / 256, 256, 0, stream>>>(C_w, Cw_bf, n4);
        cvt_bf16_vec<<<(n4 + 255) / 256, 256, 0, stream>>>(G_w, Gw_bf, n4);
        tanh_vec<<<3, 256, 0, stream>>>(a_delta, tanhd, D_);
    }

    dim3 g1(DB_ / 128, N_ / 128);    // (2, 256)
    gemm_e1_mfma<<<g1, 256, 0, stream>>>(x_bf, E1_bf, E1_b, H_bf);

    token_small<<<N_, 256, 0, stream>>>(x_bf, H_bf, V_w, U_w, E2_w, E2_b,
                                        a_base, tanhd, Lam, Bu);

    scan_pass1<<<B_ * NC_, 192, 0, stream>>>(Lam, Bu, Aagg, Send);
    scan_pass2<<<B_,       D_,  0, stream>>>(Aagg, Send, Cin);
    scan_pass3<<<B_ * NC_, 192, 0, stream>>>(Lam, Bu, Cin, S_bf);

    dim3 g2(D_ / 128, N_ / 128);     // (6, 256)
    dual_gemm_mfma<<<g2, 256, 0, stream>>>(S_bf, x_bf, Cw_bf, Gw_bf, x, G_b, out);
}

// Round 3
// 558.573 us; speedup vs baseline: 2.8744x; 1.2397x over previous
//
#include <hip/hip_runtime.h>
#include <hip/hip_bf16.h>
#include <math.h>

// Problem constants
#define B_   8
#define T_   4096
#define D_   768
#define R_   16
#define DB_  256
#define N_   (B_ * T_)      // 32768 tokens
#define NC_  64             // scan chunks per sequence
#define L_   (T_ / NC_)     // 64 steps per chunk
#define NKS_ (D_ / 32)      // 24 K-steps of 32

typedef __attribute__((ext_vector_type(8))) short bf16x8;
typedef __attribute__((ext_vector_type(4))) float f32x4;

__device__ __forceinline__ float gelu_exact(float x) {
    return 0.5f * x * (1.0f + erff(x * 0.70710678118654752f));
}
__device__ __forceinline__ float sigmoidf_(float x) {
    return 1.0f / (1.0f + expf(-x));
}
__device__ __forceinline__ float bf2f(unsigned short u) {
    return __uint_as_float(((unsigned)u) << 16);
}
__device__ __forceinline__ unsigned short f2bf(float f) {
    __hip_bfloat16 h = __float2bfloat16(f);   // RNE
    return *(unsigned short*)&h;
}

// async global->LDS, 16B per lane. LDS dest = wave-uniform base + lane*16.
__device__ __forceinline__ void gload16(const unsigned short* g, unsigned short* l) {
    __builtin_amdgcn_global_load_lds(
        (const __attribute__((address_space(1))) unsigned int*)(const void*)g,
        (__attribute__((address_space(3))) unsigned int*)(void*)l,
        16, 0, 0);
}

// ---------------------------------------------------------------------------
// Stage a 128x32 bf16 tile from row-major src (ld elems) into LDS.
// LDS slot (row,q) holds global quad q^((row>>1)&3): swizzle the SOURCE,
// keep the LDS destination linear (global_load_lds requirement, rule 21).
// ---------------------------------------------------------------------------
__device__ __forceinline__ void stage_tile(const unsigned short* src, int ld,
                                           int row0, int k0,
                                           unsigned short* lds, int w, int l) {
#pragma unroll
    for (int j = 0; j < 2; ++j) {
        int i   = ((w * 2 + j) << 6) + l;   // 0..511 16B-chunks
        int row = i >> 2;
        int q   = i & 3;
        int qs  = q ^ ((row >> 1) & 3);
        const unsigned short* g = src + (size_t)(row0 + row) * ld + k0 + qs * 8;
        gload16(g, lds + ((w * 2 + j) << 9));
    }
}

// swizzled LDS fragment read: 8 bf16 for mfma_16x16x32
__device__ __forceinline__ bf16x8 frag_read(const unsigned short* lds, int row, int lq) {
    int q = lq ^ ((row >> 1) & 3);
    return *(const bf16x8*)(lds + row * 32 + q * 8);
}

// ---------------------------------------------------------------------------
// Shared 128x128-tile K-loop (K = 768), double-buffered, ONE barrier/K-step:
//   per iter: STAGE(next) -> ds_read(cur) -> MFMA(cur) -> __syncthreads()
// The syncthreads' vmcnt(0) drain overlaps the next-tile loads with this
// iteration's ds_read+MFMA (T3 minimum-2-phase recipe).
// ---------------------------------------------------------------------------
__device__ __forceinline__ void gemm_kloop(const unsigned short* __restrict__ A,
                                           const unsigned short* __restrict__ Bm,
                                           int row0, int col0,
                                           unsigned short* lds,   // 4 * 4096 elems
                                           int w, int l, f32x4 acc[4][4]) {
    const int lr = l & 15, lq = l >> 4;
    const int wrow = (w >> 1) * 64, wcol = (w & 1) * 64;
    unsigned short* A0 = lds;
    unsigned short* B0 = lds + 4096;
    unsigned short* A1 = lds + 8192;
    unsigned short* B1 = lds + 12288;

    stage_tile(A,  D_, row0, 0, A0, w, l);
    stage_tile(Bm, D_, col0, 0, B0, w, l);
    __syncthreads();

#pragma unroll 2
    for (int t = 0; t < NKS_; ++t) {
        unsigned short* Ac = (t & 1) ? A1 : A0;
        unsigned short* Bc = (t & 1) ? B1 : B0;
        unsigned short* An = (t & 1) ? A0 : A1;
        unsigned short* Bn = (t & 1) ? B0 : B1;
        if (t + 1 < NKS_) {
            stage_tile(A,  D_, row0, (t + 1) * 32, An, w, l);
            stage_tile(Bm, D_, col0, (t + 1) * 32, Bn, w, l);
        }
        bf16x8 a[4], b[4];
#pragma unroll
        for (int m = 0; m < 4; m++) a[m] = frag_read(Ac, wrow + m * 16 + lr, lq);
#pragma unroll
        for (int n = 0; n < 4; n++) b[n] = frag_read(Bc, wcol + n * 16 + lr, lq);
#pragma unroll
        for (int m = 0; m < 4; m++)
#pragma unroll
            for (int n = 0; n < 4; n++)
                acc[m][n] = __builtin_amdgcn_mfma_f32_16x16x32_bf16(a[m], b[n], acc[m][n], 0, 0, 0);
        __syncthreads();
    }
}

// chunked XCD swizzle (nwg % 8 == 0), then col-fastest decode
__device__ __forceinline__ void tile_decode(int nwg, int ncol, int& rowt, int& colt) {
    int bid = blockIdx.x;
    int cpx = nwg >> 3;
    int swz = (bid & 7) * cpx + (bid >> 3);
    colt = swz % ncol;
    rowt = swz / ncol;
}

// ---------------------------------------------------------------------------
// H = gelu(Xb @ E1^T + b) -> bf16     grid: 512 blocks (2 cols x 256 rows)
// ---------------------------------------------------------------------------
__global__ __launch_bounds__(256)
void gemm_e1_mfma(const unsigned short* __restrict__ Xb,
                  const unsigned short* __restrict__ Wb,
                  const float* __restrict__ bias,
                  unsigned short* __restrict__ H) {
    __shared__ unsigned short lds[4 * 4096];
    const int t = threadIdx.x, l = t & 63, w = t >> 6;
    int rowt, colt;
    tile_decode(512, 2, rowt, colt);
    const int row0 = rowt * 128, col0 = colt * 128;
    const int lr = l & 15, lq = l >> 4;
    const int wrow = (w >> 1) * 64, wcol = (w & 1) * 64;
    f32x4 acc[4][4] = {};
    gemm_kloop(Xb, Wb, row0, col0, lds, w, l, acc);
#pragma unroll
    for (int m = 0; m < 4; m++)
#pragma unroll
        for (int n = 0; n < 4; n++) {
            int col = col0 + wcol + n * 16 + lr;
            float bc = bias[col];
#pragma unroll
            for (int r = 0; r < 4; r++) {
                int row = row0 + wrow + m * 16 + lq * 4 + r;
                H[(size_t)row * DB_ + col] = f2bf(gelu_exact(acc[m][n][r] + bc));
            }
        }
}

// ---------------------------------------------------------------------------
// gate = sigmoid(Xb @ G^T + Gb) -> bf16    grid: 1536 (6 cols x 256 rows)
// ---------------------------------------------------------------------------
__global__ __launch_bounds__(256)
void gemm_gate_mfma(const unsigned short* __restrict__ Xb,
                    const unsigned short* __restrict__ Gwb,
                    const float* __restrict__ Gbias,
                    unsigned short* __restrict__ gate) {
    __shared__ unsigned short lds[4 * 4096];
    const int t = threadIdx.x, l = t & 63, w = t >> 6;
    int rowt, colt;
    tile_decode(1536, 6, rowt, colt);
    const int row0 = rowt * 128, col0 = colt * 128;
    const int lr = l & 15, lq = l >> 4;
    const int wrow = (w >> 1) * 64, wcol = (w & 1) * 64;
    f32x4 acc[4][4] = {};
    gemm_kloop(Xb, Gwb, row0, col0, lds, w, l, acc);
#pragma unroll
    for (int m = 0; m < 4; m++)
#pragma unroll
        for (int n = 0; n < 4; n++) {
            int col = col0 + wcol + n * 16 + lr;
            float gb = Gbias[col];
#pragma unroll
            for (int r = 0; r < 4; r++) {
                int row = row0 + wrow + m * 16 + lq * 4 + r;
                gate[(size_t)row * D_ + col] = f2bf(sigmoidf_(acc[m][n][r] + gb));
            }
        }
}

// ---------------------------------------------------------------------------
// out = x32 + gelu(S @ C^T) * gate      grid: 1536 (6 cols x 256 rows)
// ---------------------------------------------------------------------------
__global__ __launch_bounds__(256)
void gemm_c_out_mfma(const unsigned short* __restrict__ Sb,
                     const unsigned short* __restrict__ Cwb,
                     const unsigned short* __restrict__ gate,
                     const float* __restrict__ X32,
                     float* __restrict__ out) {
    __shared__ unsigned short lds[4 * 4096];
    const int t = threadIdx.x, l = t & 63, w = t >> 6;
    int rowt, colt;
    tile_decode(1536, 6, rowt, colt);
    const int row0 = rowt * 128, col0 = colt * 128;
    const int lr = l & 15, lq = l >> 4;
    const int wrow = (w >> 1) * 64, wcol = (w & 1) * 64;
    f32x4 acc[4][4] = {};
    gemm_kloop(Sb, Cwb, row0, col0, lds, w, l, acc);
#pragma unroll
    for (int m = 0; m < 4; m++)
#pragma unroll
        for (int n = 0; n < 4; n++) {
            int col = col0 + wcol + n * 16 + lr;
#pragma unroll
            for (int r = 0; r < 4; r++) {
                int row = row0 + wrow + m * 16 + lq * 4 + r;
                size_t o = (size_t)row * D_ + col;
                float y = gelu_exact(acc[m][n][r]);
                out[o] = X32[o] + y * bf2f(gate[o]);
            }
        }
}

// ---------------------------------------------------------------------------
// Per token: Z = x@V^T, alpha = sigmoid(h@E2^T+b), Bu = Z@U^T,
//            lam = sigmoid(a_base + alpha_rep * tanh(a_delta))
// ---------------------------------------------------------------------------
__global__ __launch_bounds__(256)
void token_small(const unsigned short* __restrict__ Xb, const unsigned short* __restrict__ H,
                 const float* __restrict__ Vw, const float* __restrict__ Uw,
                 const float* __restrict__ E2w, const float* __restrict__ E2b,
                 const float* __restrict__ a_base, const float* __restrict__ tanhd,
                 unsigned short* __restrict__ Lam, unsigned short* __restrict__ Bu) {
    __shared__ float xs[D_];
    __shared__ float Zs[R_];
    __shared__ float alphas[3];
    __shared__ float red[3][4];
    const int t = threadIdx.x;
    const size_t tok = blockIdx.x;
    if (t < 192) {
        ushort4 v = *(const ushort4*)&Xb[tok * D_ + t * 4];
        xs[t * 4 + 0] = bf2f(v.x); xs[t * 4 + 1] = bf2f(v.y);
        xs[t * 4 + 2] = bf2f(v.z); xs[t * 4 + 3] = bf2f(v.w);
    }
    __syncthreads();

    {   // Z[g]: 16 groups of 16 lanes
        const int g = t >> 4, j = t & 15;
        const float* vrow = Vw + g * D_;
        float z = 0.f;
        for (int i = j; i < D_; i += 16) z = fmaf(xs[i], vrow[i], z);
        z += __shfl_xor(z, 1); z += __shfl_xor(z, 2);
        z += __shfl_xor(z, 4); z += __shfl_xor(z, 8);
        if (j == 0) Zs[g] = z;
    }
    {   // alpha partials
        float hv = bf2f(H[tok * DB_ + t]);
        float p0 = hv * E2w[0 * DB_ + t];
        float p1 = hv * E2w[1 * DB_ + t];
        float p2 = hv * E2w[2 * DB_ + t];
#pragma unroll
        for (int m = 32; m >= 1; m >>= 1) {
            p0 += __shfl_xor(p0, m);
            p1 += __shfl_xor(p1, m);
            p2 += __shfl_xor(p2, m);
        }
        int lane = t & 63, wave = t >> 6;
        if (lane == 0) { red[0][wave] = p0; red[1][wave] = p1; red[2][wave] = p2; }
    }
    __syncthreads();
    if (t < 3) {
        float s = red[t][0] + red[t][1] + red[t][2] + red[t][3];
        alphas[t] = sigmoidf_(s + E2b[t]);
    }
    __syncthreads();

#pragma unroll
    for (int ch = 0; ch < 3; ch++) {
        int d = t + 256 * ch;
        const float4* u4 = (const float4*)(Uw + (size_t)d * R_);
        float4 u0 = u4[0], u1 = u4[1], u2 = u4[2], u3 = u4[3];
        float bu = Zs[0]  * u0.x + Zs[1]  * u0.y + Zs[2]  * u0.z + Zs[3]  * u0.w
                 + Zs[4]  * u1.x + Zs[5]  * u1.y + Zs[6]  * u1.z + Zs[7]  * u1.w
                 + Zs[8]  * u2.x + Zs[9]  * u2.y + Zs[10] * u2.z + Zs[11] * u2.w
                 + Zs[12] * u3.x + Zs[13] * u3.y + Zs[14] * u3.z + Zs[15] * u3.w;
        float a_eff = a_base[d] + alphas[ch] * tanhd[d];
        size_t o = tok * D_ + d;
        Bu[o]  = f2bf(bu);
        Lam[o] = f2bf(sigmoidf_(a_eff));   // exp(-softplus(-a)) == sigmoid(a)
    }
}

// ---------------------------------------------------------------------------
// Chunked parallel scan: s_t = lam_t * s_{t-1} + bu_t  (bf16 in, fp32 state)
// ---------------------------------------------------------------------------
__global__ void scan_pass1(const unsigned short* __restrict__ lam,
                           const unsigned short* __restrict__ bu,
                           float* __restrict__ Aagg, float* __restrict__ Send) {
    const int th = threadIdx.x;             // 0..191
    const int c = blockIdx.x & (NC_ - 1);
    const int b = blockIdx.x >> 6;
    const size_t base = ((size_t)(b * T_ + c * L_)) * D_ + th * 4;
    float a[4] = {1.f, 1.f, 1.f, 1.f}, s[4] = {};
    for (int i = 0; i < L_; i++) {
        ushort4 lv = *(const ushort4*)&lam[base + (size_t)i * D_];
        ushort4 uv = *(const ushort4*)&bu [base + (size_t)i * D_];
        float lf[4] = {bf2f(lv.x), bf2f(lv.y), bf2f(lv.z), bf2f(lv.w)};
        float uf[4] = {bf2f(uv.x), bf2f(uv.y), bf2f(uv.z), bf2f(uv.w)};
#pragma unroll
        for (int j = 0; j < 4; j++) { a[j] *= lf[j]; s[j] = fmaf(lf[j], s[j], uf[j]); }
    }
    size_t o = ((size_t)(b * NC_ + c)) * D_ + th * 4;
#pragma unroll
    for (int j = 0; j < 4; j++) { Aagg[o + j] = a[j]; Send[o + j] = s[j]; }
}

__global__ void scan_pass2(const float* __restrict__ Aagg, const float* __restrict__ Send,
                           float* __restrict__ Cin) {
    const int d = threadIdx.x;              // 768 threads
    const int b = blockIdx.x;               // 8 blocks
    float s = 0.f;
    for (int c = 0; c < NC_; c++) {
        size_t o = ((size_t)(b * NC_ + c)) * D_ + d;
        Cin[o] = s;
        s = fmaf(Aagg[o], s, Send[o]);
    }
}

__global__ void scan_pass3(const unsigned short* __restrict__ lam,
                           const unsigned short* __restrict__ bu,
                           const float* __restrict__ Cin,
                           unsigned short* __restrict__ Sout) {
    const int th = threadIdx.x;
    const int c = blockIdx.x & (NC_ - 1);
    const int b = blockIdx.x >> 6;
    const size_t base = ((size_t)(b * T_ + c * L_)) * D_ + th * 4;
    size_t ci = ((size_t)(b * NC_ + c)) * D_ + th * 4;
    float s[4] = {Cin[ci], Cin[ci + 1], Cin[ci + 2], Cin[ci + 3]};
    for (int i = 0; i < L_; i++) {
        size_t o = base + (size_t)i * D_;
        ushort4 lv = *(const ushort4*)&lam[o];
        ushort4 uv = *(const ushort4*)&bu[o];
        float lf[4] = {bf2f(lv.x), bf2f(lv.y), bf2f(lv.z), bf2f(lv.w)};
        float uf[4] = {bf2f(uv.x), bf2f(uv.y), bf2f(uv.z), bf2f(uv.w)};
#pragma unroll
        for (int j = 0; j < 4; j++) s[j] = fmaf(lf[j], s[j], uf[j]);
        ushort4 ov = make_ushort4(f2bf(s[0]), f2bf(s[1]), f2bf(s[2]), f2bf(s[3]));
        *(ushort4*)&Sout[o] = ov;
    }
}

// ---------------------------------------------------------------------------
// small conversion kernels
// ---------------------------------------------------------------------------
__global__ void cvt_bf16_vec(const float* __restrict__ in, unsigned short* __restrict__ out, int n4) {
    int i = blockIdx.x * 256 + threadIdx.x;
    if (i < n4) {
        float4 v = ((const float4*)in)[i];
        ((ushort4*)out)[i] = make_ushort4(f2bf(v.x), f2bf(v.y), f2bf(v.z), f2bf(v.w));
    }
}
__global__ void tanh_vec(const float* __restrict__ in, float* __restrict__ out, int n) {
    int i = blockIdx.x * 256 + threadIdx.x;
    if (i < n) out[i] = tanhf(in[i]);
}

// ---------------------------------------------------------------------------
extern "C" void kernel_launch(void* const* d_in, const int* in_sizes, int n_in,
                              void* d_out, int out_size, void* d_ws, size_t ws_size,
                              hipStream_t stream) {
    const float* x       = (const float*)d_in[0];
    const float* V_w     = (const float*)d_in[1];
    const float* U_w     = (const float*)d_in[2];
    const float* E1_w    = (const float*)d_in[3];
    const float* E1_b    = (const float*)d_in[4];
    const float* E2_w    = (const float*)d_in[5];
    const float* E2_b    = (const float*)d_in[6];
    const float* a_base  = (const float*)d_in[7];
    const float* a_delta = (const float*)d_in[8];
    const float* C_w     = (const float*)d_in[9];
    const float* G_w     = (const float*)d_in[10];
    const float* G_b     = (const float*)d_in[11];
    float* out = (float*)d_out;

    // workspace layout
    char* p = (char*)d_ws;
    float* Aagg  = (float*)p;           p += (size_t)B_ * NC_ * D_ * 4;
    float* Send  = (float*)p;           p += (size_t)B_ * NC_ * D_ * 4;
    float* Cin   = (float*)p;           p += (size_t)B_ * NC_ * D_ * 4;
    float* tanhd = (float*)p;           p += (size_t)D_ * 4;
    unsigned short* x_bf  = (unsigned short*)p; p += (size_t)N_ * D_ * 2;
    unsigned short* H_bf  = (unsigned short*)p; p += (size_t)N_ * DB_ * 2;
    unsigned short* Lam   = (unsigned short*)p; p += (size_t)N_ * D_ * 2;   // becomes gate after scan
    unsigned short* Bu    = (unsigned short*)p; p += (size_t)N_ * D_ * 2;
    unsigned short* S_bf  = (unsigned short*)p; p += (size_t)N_ * D_ * 2;
    unsigned short* E1_bf = (unsigned short*)p; p += (size_t)DB_ * D_ * 2;
    unsigned short* Cw_bf = (unsigned short*)p; p += (size_t)D_ * D_ * 2;
    unsigned short* Gw_bf = (unsigned short*)p; p += (size_t)D_ * D_ * 2;

    // conversions
    {
        int n4 = N_ * D_ / 4;
        cvt_bf16_vec<<<(n4 + 255) / 256, 256, 0, stream>>>(x, x_bf, n4);
        n4 = DB_ * D_ / 4;
        cvt_bf16_vec<<<(n4 + 255) / 256, 256, 0, stream>>>(E1_w, E1_bf, n4);
        n4 = D_ * D_ / 4;
        cvt_bf16_vec<<<(n4 + 255) / 256, 256, 0, stream>>>(C_w, Cw_bf, n4);
        cvt_bf16_vec<<<(n4 + 255) / 256, 256, 0, stream>>>(G_w, Gw_bf, n4);
        tanh_vec<<<3, 256, 0, stream>>>(a_delta, tanhd, D_);
    }

    gemm_e1_mfma<<<512, 256, 0, stream>>>(x_bf, E1_bf, E1_b, H_bf);

    token_small<<<N_, 256, 0, stream>>>(x_bf, H_bf, V_w, U_w, E2_w, E2_b,
                                        a_base, tanhd, Lam, Bu);

    scan_pass1<<<B_ * NC_, 192, 0, stream>>>(Lam, Bu, Aagg, Send);
    scan_pass2<<<B_,       D_,  0, stream>>>(Aagg, Send, Cin);
    scan_pass3<<<B_ * NC_, 192, 0, stream>>>(Lam, Bu, Cin, S_bf);

    // gate overwrites Lam (dead after scan_pass3)
    unsigned short* gate = Lam;
    gemm_gate_mfma<<<1536, 256, 0, stream>>>(x_bf, Gw_bf, G_b, gate);
    gemm_c_out_mfma<<<1536, 256, 0, stream>>>(S_bf, Cw_bf, gate, x, out);
}

// Round 4
// 387.250 us; speedup vs baseline: 4.1460x; 1.4424x over previous
//
#include <hip/hip_runtime.h>
#include <hip/hip_bf16.h>
#include <math.h>

// Problem constants
#define B_   8
#define T_   4096
#define D_   768
#define R_   16
#define DB_  256
#define N_   (B_ * T_)      // 32768 tokens
#define NC_  64             // scan chunks per sequence
#define L_   (T_ / NC_)     // 64 steps per chunk
#define NKS_ (D_ / 32)      // 24 K-steps of 32

typedef __attribute__((ext_vector_type(8))) short bf16x8;
typedef __attribute__((ext_vector_type(4))) float f32x4;

__device__ __forceinline__ float gelu_exact(float x) {
    return 0.5f * x * (1.0f + erff(x * 0.70710678118654752f));
}
__device__ __forceinline__ float sigmoidf_(float x) {
    return 1.0f / (1.0f + expf(-x));
}
__device__ __forceinline__ float bf2f(unsigned short u) {
    return __uint_as_float(((unsigned)u) << 16);
}
__device__ __forceinline__ unsigned short f2bf(float f) {
    __hip_bfloat16 h = __float2bfloat16(f);   // RNE
    return *(unsigned short*)&h;
}

// async global->LDS, 16B per lane. LDS dest = wave-uniform base + lane*16.
__device__ __forceinline__ void gload16(const unsigned short* g, unsigned short* l) {
    __builtin_amdgcn_global_load_lds(
        (const __attribute__((address_space(1))) unsigned int*)(const void*)g,
        (__attribute__((address_space(3))) unsigned int*)(void*)l,
        16, 0, 0);
}

// ---------------------------------------------------------------------------
// Stage a 128x32 bf16 tile into LDS; swizzle the SOURCE quad, linear LDS dest.
// ---------------------------------------------------------------------------
__device__ __forceinline__ void stage_tile(const unsigned short* src, int ld,
                                           int row0, int k0,
                                           unsigned short* lds, int w, int l) {
#pragma unroll
    for (int j = 0; j < 2; ++j) {
        int i   = ((w * 2 + j) << 6) + l;   // 0..511 16B-chunks
        int row = i >> 2;
        int q   = i & 3;
        int qs  = q ^ ((row >> 1) & 3);
        const unsigned short* g = src + (size_t)(row0 + row) * ld + k0 + qs * 8;
        gload16(g, lds + ((w * 2 + j) << 9));
    }
}

// swizzled LDS fragment read: 8 bf16 for mfma_16x16x32
__device__ __forceinline__ bf16x8 frag_read(const unsigned short* lds, int row, int lq) {
    int q = lq ^ ((row >> 1) & 3);
    return *(const bf16x8*)(lds + row * 32 + q * 8);
}

// ---------------------------------------------------------------------------
// 128x128-tile K-loop (K=768), double-buffered, one barrier per K-step.
// ---------------------------------------------------------------------------
__device__ __forceinline__ void gemm_kloop(const unsigned short* __restrict__ A,
                                           const unsigned short* __restrict__ Bm,
                                           int row0, int col0,
                                           unsigned short* lds,   // 4 * 4096 elems
                                           int w, int l, f32x4 acc[4][4]) {
    const int lr = l & 15, lq = l >> 4;
    const int wrow = (w >> 1) * 64, wcol = (w & 1) * 64;
    unsigned short* A0 = lds;
    unsigned short* B0 = lds + 4096;
    unsigned short* A1 = lds + 8192;
    unsigned short* B1 = lds + 12288;

    stage_tile(A,  D_, row0, 0, A0, w, l);
    stage_tile(Bm, D_, col0, 0, B0, w, l);
    __syncthreads();

#pragma unroll 2
    for (int t = 0; t < NKS_; ++t) {
        unsigned short* Ac = (t & 1) ? A1 : A0;
        unsigned short* Bc = (t & 1) ? B1 : B0;
        unsigned short* An = (t & 1) ? A0 : A1;
        unsigned short* Bn = (t & 1) ? B0 : B1;
        if (t + 1 < NKS_) {
            stage_tile(A,  D_, row0, (t + 1) * 32, An, w, l);
            stage_tile(Bm, D_, col0, (t + 1) * 32, Bn, w, l);
        }
        bf16x8 a[4], b[4];
#pragma unroll
        for (int m = 0; m < 4; m++) a[m] = frag_read(Ac, wrow + m * 16 + lr, lq);
#pragma unroll
        for (int n = 0; n < 4; n++) b[n] = frag_read(Bc, wcol + n * 16 + lr, lq);
#pragma unroll
        for (int m = 0; m < 4; m++)
#pragma unroll
            for (int n = 0; n < 4; n++)
                acc[m][n] = __builtin_amdgcn_mfma_f32_16x16x32_bf16(a[m], b[n], acc[m][n], 0, 0, 0);
        __syncthreads();
    }
}

// chunked XCD swizzle (nwg % 8 == 0), then col-fastest decode
__device__ __forceinline__ void tile_decode(int nwg, int ncol, int& rowt, int& colt) {
    int bid = blockIdx.x;
    int cpx = nwg >> 3;
    int swz = (bid & 7) * cpx + (bid >> 3);
    colt = swz % ncol;
    rowt = swz / ncol;
}

// ---------------------------------------------------------------------------
// H = gelu(Xb @ E1^T + b) -> bf16     grid: 512 blocks (2 cols x 256 rows)
// ---------------------------------------------------------------------------
__global__ __launch_bounds__(256)
void gemm_e1_mfma(const unsigned short* __restrict__ Xb,
                  const unsigned short* __restrict__ Wb,
                  const float* __restrict__ bias,
                  unsigned short* __restrict__ H) {
    __shared__ unsigned short lds[4 * 4096];
    const int t = threadIdx.x, l = t & 63, w = t >> 6;
    int rowt, colt;
    tile_decode(512, 2, rowt, colt);
    const int row0 = rowt * 128, col0 = colt * 128;
    const int lr = l & 15, lq = l >> 4;
    const int wrow = (w >> 1) * 64, wcol = (w & 1) * 64;
    f32x4 acc[4][4] = {};
    gemm_kloop(Xb, Wb, row0, col0, lds, w, l, acc);
#pragma unroll
    for (int m = 0; m < 4; m++)
#pragma unroll
        for (int n = 0; n < 4; n++) {
            int col = col0 + wcol + n * 16 + lr;
            float bc = bias[col];
#pragma unroll
            for (int r = 0; r < 4; r++) {
                int row = row0 + wrow + m * 16 + lq * 4 + r;
                H[(size_t)row * DB_ + col] = f2bf(gelu_exact(acc[m][n][r] + bc));
            }
        }
}

// ---------------------------------------------------------------------------
// gate = sigmoid(Xb @ G^T + Gb) -> bf16    grid: 1536 (6 cols x 256 rows)
// ---------------------------------------------------------------------------
__global__ __launch_bounds__(256)
void gemm_gate_mfma(const unsigned short* __restrict__ Xb,
                    const unsigned short* __restrict__ Gwb,
                    const float* __restrict__ Gbias,
                    unsigned short* __restrict__ gate) {
    __shared__ unsigned short lds[4 * 4096];
    const int t = threadIdx.x, l = t & 63, w = t >> 6;
    int rowt, colt;
    tile_decode(1536, 6, rowt, colt);
    const int row0 = rowt * 128, col0 = colt * 128;
    const int lr = l & 15, lq = l >> 4;
    const int wrow = (w >> 1) * 64, wcol = (w & 1) * 64;
    f32x4 acc[4][4] = {};
    gemm_kloop(Xb, Gwb, row0, col0, lds, w, l, acc);
#pragma unroll
    for (int m = 0; m < 4; m++)
#pragma unroll
        for (int n = 0; n < 4; n++) {
            int col = col0 + wcol + n * 16 + lr;
            float gb = Gbias[col];
#pragma unroll
            for (int r = 0; r < 4; r++) {
                int row = row0 + wrow + m * 16 + lq * 4 + r;
                gate[(size_t)row * D_ + col] = f2bf(sigmoidf_(acc[m][n][r] + gb));
            }
        }
}

// ---------------------------------------------------------------------------
// out = x32 + gelu(S @ C^T) * gate      grid: 1536 (6 cols x 256 rows)
// ---------------------------------------------------------------------------
__global__ __launch_bounds__(256)
void gemm_c_out_mfma(const unsigned short* __restrict__ Sb,
                     const unsigned short* __restrict__ Cwb,
                     const unsigned short* __restrict__ gate,
                     const float* __restrict__ X32,
                     float* __restrict__ out) {
    __shared__ unsigned short lds[4 * 4096];
    const int t = threadIdx.x, l = t & 63, w = t >> 6;
    int rowt, colt;
    tile_decode(1536, 6, rowt, colt);
    const int row0 = rowt * 128, col0 = colt * 128;
    const int lr = l & 15, lq = l >> 4;
    const int wrow = (w >> 1) * 64, wcol = (w & 1) * 64;
    f32x4 acc[4][4] = {};
    gemm_kloop(Sb, Cwb, row0, col0, lds, w, l, acc);
#pragma unroll
    for (int m = 0; m < 4; m++)
#pragma unroll
        for (int n = 0; n < 4; n++) {
            int col = col0 + wcol + n * 16 + lr;
#pragma unroll
            for (int r = 0; r < 4; r++) {
                int row = row0 + wrow + m * 16 + lq * 4 + r;
                size_t o = (size_t)row * D_ + col;
                float y = gelu_exact(acc[m][n][r]);
                out[o] = X32[o] + y * bf2f(gate[o]);
            }
        }
}

// ---------------------------------------------------------------------------
// Z = Xb @ V^T : (N x 768)(16 x 768)^T -> N x 16 fp32.
// One wave = 16 tokens; block = 4 waves = 64 tokens; grid 512.
// ---------------------------------------------------------------------------
__global__ __launch_bounds__(256)
void z_mfma(const unsigned short* __restrict__ Xb,
            const unsigned short* __restrict__ Vb,
            float* __restrict__ Z) {
    const int t = threadIdx.x, l = t & 63, w = t >> 6;
    const int lr = l & 15, lq = l >> 4;
    const int tok0 = (blockIdx.x * 4 + w) * 16;
    f32x4 acc = {};
#pragma unroll
    for (int k0 = 0; k0 < D_; k0 += 32) {
        bf16x8 a = *(const bf16x8*)&Xb[(size_t)(tok0 + lr) * D_ + k0 + lq * 8];
        bf16x8 b = *(const bf16x8*)&Vb[(size_t)lr * D_ + k0 + lq * 8];
        acc = __builtin_amdgcn_mfma_f32_16x16x32_bf16(a, b, acc, 0, 0, 0);
    }
    // D layout: col(=r) = lane&15, row(=token) = (lane>>4)*4 + reg
#pragma unroll
    for (int rr = 0; rr < 4; rr++)
        Z[(size_t)(tok0 + lq * 4 + rr) * R_ + lr] = acc[rr];
}

// ---------------------------------------------------------------------------
// alpha[tok][c] = sigmoid(sum_e h[tok][e]*E2w[c][e] + E2b[c])
// one wave per token (4 e per lane); block = 4 waves; grid 8192.
// ---------------------------------------------------------------------------
__global__ __launch_bounds__(256)
void alpha_kernel(const unsigned short* __restrict__ H,
                  const float* __restrict__ E2w, const float* __restrict__ E2b,
                  float* __restrict__ alpha) {
    const int t = threadIdx.x, l = t & 63, w = t >> 6;
    const size_t tok = blockIdx.x * 4 + w;
    ushort4 hv = *(const ushort4*)&H[tok * DB_ + l * 4];
    float h0 = bf2f(hv.x), h1 = bf2f(hv.y), h2 = bf2f(hv.z), h3 = bf2f(hv.w);
    float p[3];
#pragma unroll
    for (int c = 0; c < 3; c++) {
        float4 e = *(const float4*)&E2w[c * DB_ + l * 4];
        p[c] = h0 * e.x + h1 * e.y + h2 * e.z + h3 * e.w;
#pragma unroll
        for (int m = 32; m >= 1; m >>= 1) p[c] += __shfl_xor(p[c], m);
    }
    if (l == 0) {
        alpha[tok * 3 + 0] = sigmoidf_(p[0] + E2b[0]);
        alpha[tok * 3 + 1] = sigmoidf_(p[1] + E2b[1]);
        alpha[tok * 3 + 2] = sigmoidf_(p[2] + E2b[2]);
    }
}

// ---------------------------------------------------------------------------
// Scan with on-the-fly lam/bu recompute.
//   lam = sigmoid(a_base[d] + alpha[tok][c]*tanhd[d]);  bu = Z[tok]·U[d]
// Block = (b,chunk): 192 threads x 4 channels. Z chunk + alpha staged in LDS.
// ---------------------------------------------------------------------------
__device__ __forceinline__ void load_chunk_lds(const float* __restrict__ Z,
                                               const float* __restrict__ alpha,
                                               int tok0, int t,
                                               float* Zs, float* als) {
#pragma unroll
    for (int i = t; i < L_ * R_ / 4; i += 192)
        *(float4*)&Zs[i * 4] = *(const float4*)&Z[(size_t)tok0 * R_ + i * 4];
    als[t] = alpha[(size_t)tok0 * 3 + t];   // exactly 192 = 64*3
}

__device__ __forceinline__ float dot16(const float* zrow, const float4* u) {
    float4 z0 = *(const float4*)&zrow[0],  z1 = *(const float4*)&zrow[4];
    float4 z2 = *(const float4*)&zrow[8],  z3 = *(const float4*)&zrow[12];
    return z0.x*u[0].x + z0.y*u[0].y + z0.z*u[0].z + z0.w*u[0].w
         + z1.x*u[1].x + z1.y*u[1].y + z1.z*u[1].z + z1.w*u[1].w
         + z2.x*u[2].x + z2.y*u[2].y + z2.z*u[2].z + z2.w*u[2].w
         + z3.x*u[3].x + z3.y*u[3].y + z3.z*u[3].z + z3.w*u[3].w;
}

__global__ __launch_bounds__(192)
void scan_pass1(const float* __restrict__ Z, const float* __restrict__ alpha,
                const float* __restrict__ Uw, const float* __restrict__ a_base,
                const float* __restrict__ tanhd,
                float* __restrict__ Aagg, float* __restrict__ Send) {
    __shared__ float Zs[L_ * R_];
    __shared__ float als[L_ * 3];
    const int t = threadIdx.x;
    const int c = blockIdx.x & (NC_ - 1);
    const int b = blockIdx.x >> 6;
    const int tok0 = b * T_ + c * L_;
    const int d0 = t * 4;
    const int buck = d0 >> 8;
    load_chunk_lds(Z, alpha, tok0, t, Zs, als);

    float4 u[4][4];
#pragma unroll
    for (int j = 0; j < 4; j++)
#pragma unroll
        for (int q = 0; q < 4; q++)
            u[j][q] = *(const float4*)&Uw[(size_t)(d0 + j) * R_ + q * 4];
    float4 ab = *(const float4*)&a_base[d0];
    float4 td = *(const float4*)&tanhd[d0];
    float abv[4] = {ab.x, ab.y, ab.z, ab.w};
    float tdv[4] = {td.x, td.y, td.z, td.w};
    __syncthreads();

    float a[4] = {1.f, 1.f, 1.f, 1.f}, s[4] = {};
    for (int i = 0; i < L_; i++) {
        float av = als[i * 3 + buck];
#pragma unroll
        for (int j = 0; j < 4; j++) {
            float lam = sigmoidf_(fmaf(av, tdv[j], abv[j]));
            float bu  = dot16(&Zs[i * R_], u[j]);
            a[j] *= lam;
            s[j] = fmaf(lam, s[j], bu);
        }
    }
    size_t o = ((size_t)(b * NC_ + c)) * D_ + d0;
    *(float4*)&Aagg[o] = make_float4(a[0], a[1], a[2], a[3]);
    *(float4*)&Send[o] = make_float4(s[0], s[1], s[2], s[3]);
}

__global__ void scan_pass2(const float* __restrict__ Aagg, const float* __restrict__ Send,
                           float* __restrict__ Cin) {
    const int d = threadIdx.x;              // 768 threads
    const int b = blockIdx.x;               // 8 blocks
    float s = 0.f;
    for (int c = 0; c < NC_; c++) {
        size_t o = ((size_t)(b * NC_ + c)) * D_ + d;
        Cin[o] = s;
        s = fmaf(Aagg[o], s, Send[o]);
    }
}

__global__ __launch_bounds__(192)
void scan_pass3(const float* __restrict__ Z, const float* __restrict__ alpha,
                const float* __restrict__ Uw, const float* __restrict__ a_base,
                const float* __restrict__ tanhd, const float* __restrict__ Cin,
                unsigned short* __restrict__ Sout) {
    __shared__ float Zs[L_ * R_];
    __shared__ float als[L_ * 3];
    const int t = threadIdx.x;
    const int c = blockIdx.x & (NC_ - 1);
    const int b = blockIdx.x >> 6;
    const int tok0 = b * T_ + c * L_;
    const int d0 = t * 4;
    const int buck = d0 >> 8;
    load_chunk_lds(Z, alpha, tok0, t, Zs, als);

    float4 u[4][4];
#pragma unroll
    for (int j = 0; j < 4; j++)
#pragma unroll
        for (int q = 0; q < 4; q++)
            u[j][q] = *(const float4*)&Uw[(size_t)(d0 + j) * R_ + q * 4];
    float4 ab = *(const float4*)&a_base[d0];
    float4 td = *(const float4*)&tanhd[d0];
    float abv[4] = {ab.x, ab.y, ab.z, ab.w};
    float tdv[4] = {td.x, td.y, td.z, td.w};
    __syncthreads();

    size_t ci = ((size_t)(b * NC_ + c)) * D_ + d0;
    float4 c4 = *(const float4*)&Cin[ci];
    float s[4] = {c4.x, c4.y, c4.z, c4.w};
    for (int i = 0; i < L_; i++) {
        float av = als[i * 3 + buck];
#pragma unroll
        for (int j = 0; j < 4; j++) {
            float lam = sigmoidf_(fmaf(av, tdv[j], abv[j]));
            float bu  = dot16(&Zs[i * R_], u[j]);
            s[j] = fmaf(lam, s[j], bu);
        }
        *(ushort4*)&Sout[(size_t)(tok0 + i) * D_ + d0] =
            make_ushort4(f2bf(s[0]), f2bf(s[1]), f2bf(s[2]), f2bf(s[3]));
    }
}

// ---------------------------------------------------------------------------
// small conversion kernels
// ---------------------------------------------------------------------------
__global__ void cvt_bf16_vec(const float* __restrict__ in, unsigned short* __restrict__ out, int n4) {
    int i = blockIdx.x * 256 + threadIdx.x;
    if (i < n4) {
        float4 v = ((const float4*)in)[i];
        ((ushort4*)out)[i] = make_ushort4(f2bf(v.x), f2bf(v.y), f2bf(v.z), f2bf(v.w));
    }
}
__global__ void tanh_vec(const float* __restrict__ in, float* __restrict__ out, int n) {
    int i = blockIdx.x * 256 + threadIdx.x;
    if (i < n) out[i] = tanhf(in[i]);
}

// ---------------------------------------------------------------------------
extern "C" void kernel_launch(void* const* d_in, const int* in_sizes, int n_in,
                              void* d_out, int out_size, void* d_ws, size_t ws_size,
                              hipStream_t stream) {
    const float* x       = (const float*)d_in[0];
    const float* V_w     = (const float*)d_in[1];
    const float* U_w     = (const float*)d_in[2];
    const float* E1_w    = (const float*)d_in[3];
    const float* E1_b    = (const float*)d_in[4];
    const float* E2_w    = (const float*)d_in[5];
    const float* E2_b    = (const float*)d_in[6];
    const float* a_base  = (const float*)d_in[7];
    const float* a_delta = (const float*)d_in[8];
    const float* C_w     = (const float*)d_in[9];
    const float* G_w     = (const float*)d_in[10];
    const float* G_b     = (const float*)d_in[11];
    float* out = (float*)d_out;

    // workspace layout
    char* p = (char*)d_ws;
    float* Aagg  = (float*)p;           p += (size_t)B_ * NC_ * D_ * 4;
    float* Send  = (float*)p;           p += (size_t)B_ * NC_ * D_ * 4;
    float* Cin   = (float*)p;           p += (size_t)B_ * NC_ * D_ * 4;
    float* tanhd = (float*)p;           p += (size_t)D_ * 4;
    float* Z     = (float*)p;           p += (size_t)N_ * R_ * 4;
    float* alpha = (float*)p;           p += (size_t)N_ * 3 * 4;
    unsigned short* x_bf  = (unsigned short*)p; p += (size_t)N_ * D_ * 2;
    unsigned short* H_bf  = (unsigned short*)p; p += (size_t)N_ * DB_ * 2;
    unsigned short* gate  = (unsigned short*)p; p += (size_t)N_ * D_ * 2;
    unsigned short* S_bf  = (unsigned short*)p; p += (size_t)N_ * D_ * 2;
    unsigned short* E1_bf = (unsigned short*)p; p += (size_t)DB_ * D_ * 2;
    unsigned short* Cw_bf = (unsigned short*)p; p += (size_t)D_ * D_ * 2;
    unsigned short* Gw_bf = (unsigned short*)p; p += (size_t)D_ * D_ * 2;
    unsigned short* V_bf  = (unsigned short*)p; p += (size_t)R_ * D_ * 2;

    // conversions
    {
        int n4 = N_ * D_ / 4;
        cvt_bf16_vec<<<(n4 + 255) / 256, 256, 0, stream>>>(x, x_bf, n4);
        n4 = DB_ * D_ / 4;
        cvt_bf16_vec<<<(n4 + 255) / 256, 256, 0, stream>>>(E1_w, E1_bf, n4);
        n4 = D_ * D_ / 4;
        cvt_bf16_vec<<<(n4 + 255) / 256, 256, 0, stream>>>(C_w, Cw_bf, n4);
        cvt_bf16_vec<<<(n4 + 255) / 256, 256, 0, stream>>>(G_w, Gw_bf, n4);
        n4 = R_ * D_ / 4;
        cvt_bf16_vec<<<(n4 + 255) / 256, 256, 0, stream>>>(V_w, V_bf, n4);
        tanh_vec<<<3, 256, 0, stream>>>(a_delta, tanhd, D_);
    }

    gemm_e1_mfma<<<512, 256, 0, stream>>>(x_bf, E1_bf, E1_b, H_bf);
    alpha_kernel<<<N_ / 4, 256, 0, stream>>>(H_bf, E2_w, E2_b, alpha);
    z_mfma<<<N_ / 64, 256, 0, stream>>>(x_bf, V_bf, Z);

    scan_pass1<<<B_ * NC_, 192, 0, stream>>>(Z, alpha, U_w, a_base, tanhd, Aagg, Send);
    scan_pass2<<<B_,       D_,  0, stream>>>(Aagg, Send, Cin);
    scan_pass3<<<B_ * NC_, 192, 0, stream>>>(Z, alpha, U_w, a_base, tanhd, Cin, S_bf);

    gemm_gate_mfma<<<1536, 256, 0, stream>>>(x_bf, Gw_bf, G_b, gate);
    gemm_c_out_mfma<<<1536, 256, 0, stream>>>(S_bf, Cw_bf, gate, x, out);
}

// Round 5
// 341.995 us; speedup vs baseline: 4.6946x; 1.1323x over previous
//
#include <hip/hip_runtime.h>
#include <hip/hip_bf16.h>
#include <math.h>

// Problem constants
#define B_   8
#define T_   4096
#define D_   768
#define R_   16
#define DB_  256
#define N_   (B_ * T_)      // 32768 tokens
#define NC_  64             // scan chunks per sequence
#define L_   (T_ / NC_)     // 64 steps per chunk
#define NKS_ (D_ / 32)      // 24 K-steps of 32

typedef __attribute__((ext_vector_type(8))) short bf16x8;
typedef __attribute__((ext_vector_type(4))) float f32x4;

__device__ __forceinline__ float gelu_exact(float x) {
    return 0.5f * x * (1.0f + erff(x * 0.70710678118654752f));
}
__device__ __forceinline__ float sigmoidf_(float x) {
    return 1.0f / (1.0f + expf(-x));
}
__device__ __forceinline__ float bf2f(unsigned short u) {
    return __uint_as_float(((unsigned)u) << 16);
}
__device__ __forceinline__ unsigned short f2bf(float f) {
    __hip_bfloat16 h = __float2bfloat16(f);   // RNE
    return *(unsigned short*)&h;
}

// async global->LDS, 16B per lane. LDS dest = wave-uniform base + lane*16.
__device__ __forceinline__ void gload16(const unsigned short* g, unsigned short* l) {
    __builtin_amdgcn_global_load_lds(
        (const __attribute__((address_space(1))) unsigned int*)(const void*)g,
        (__attribute__((address_space(3))) unsigned int*)(void*)l,
        16, 0, 0);
}

// ---------------------------------------------------------------------------
// Stage a 128x32 bf16 tile into LDS; swizzle the SOURCE quad, linear LDS dest
// (rule 21: source permutation == read permutation, LDS dest stays linear).
// 2 gloads per thread per tile -> 4 per K-tile (A+B).
// ---------------------------------------------------------------------------
__device__ __forceinline__ void stage_tile(const unsigned short* src, int ld,
                                           int row0, int k0,
                                           unsigned short* lds, int w, int l) {
#pragma unroll
    for (int j = 0; j < 2; ++j) {
        int i   = ((w * 2 + j) << 6) + l;   // 0..511 16B-chunks
        int row = i >> 2;
        int q   = i & 3;
        int qs  = q ^ ((row >> 1) & 3);
        const unsigned short* g = src + (size_t)(row0 + row) * ld + k0 + qs * 8;
        gload16(g, lds + ((w * 2 + j) << 9));
    }
}

// swizzled LDS fragment read: 8 bf16 for mfma_16x16x32 (bank-conflict-free)
__device__ __forceinline__ bf16x8 frag_read(const unsigned short* lds, int row, int lq) {
    int q = lq ^ ((row >> 1) & 3);
    return *(const bf16x8*)(lds + row * 32 + q * 8);
}

__device__ __forceinline__ void tile_mfma(const unsigned short* bc,
                                          int wrow, int wcol, int lr, int lq,
                                          f32x4 acc[4][4]) {
    bf16x8 a[4], b[4];
#pragma unroll
    for (int m = 0; m < 4; m++) a[m] = frag_read(bc, wrow + m * 16 + lr, lq);
#pragma unroll
    for (int n = 0; n < 4; n++) b[n] = frag_read(bc + 4096, wcol + n * 16 + lr, lq);
#pragma unroll
    for (int m = 0; m < 4; m++)
#pragma unroll
        for (int n = 0; n < 4; n++)
            acc[m][n] = __builtin_amdgcn_mfma_f32_16x16x32_bf16(a[m], b[n], acc[m][n], 0, 0, 0);
}

// ---------------------------------------------------------------------------
// 128x128-tile K-loop, 3-deep pipeline with counted vmcnt (never drains to 0
// in the main loop). Per iter: wait own tile-t loads (vmcnt(4): 8 in flight,
// oldest 4 = tile t) -> barrier (all waves' tile-t LDS writes visible; all
// prior reads of buf[(t+2)%3] consumed) -> issue stage(t+2) -> compute(t).
// ---------------------------------------------------------------------------
__device__ __forceinline__ void kloop3(const unsigned short* __restrict__ A,
                                       const unsigned short* __restrict__ Bm,
                                       int row0, int col0,
                                       unsigned short* lds,   // 3 * 8192 elems
                                       int w, int l, f32x4 acc[4][4]) {
    const int lr = l & 15, lq = l >> 4;
    const int wrow = (w >> 1) * 64, wcol = (w & 1) * 64;

    stage_tile(A,  D_, row0, 0,  lds,         w, l);
    stage_tile(Bm, D_, col0, 0,  lds + 4096,  w, l);
    stage_tile(A,  D_, row0, 32, lds + 8192,  w, l);
    stage_tile(Bm, D_, col0, 32, lds + 12288, w, l);

#pragma unroll 3
    for (int t = 0; t < NKS_ - 2; ++t) {
        asm volatile("s_waitcnt vmcnt(4)" ::: "memory");
        __builtin_amdgcn_s_barrier();
        __builtin_amdgcn_sched_barrier(0);
        unsigned short* bn = lds + ((t + 2) % 3) * 8192;
        stage_tile(A,  D_, row0, (t + 2) * 32, bn,        w, l);
        stage_tile(Bm, D_, col0, (t + 2) * 32, bn + 4096, w, l);
        tile_mfma(lds + (t % 3) * 8192, wrow, wcol, lr, lq, acc);
    }
    // t = NKS_-2: tiles NKS_-2 (oldest 4) + NKS_-1 in flight
    asm volatile("s_waitcnt vmcnt(4)" ::: "memory");
    __builtin_amdgcn_s_barrier();
    __builtin_amdgcn_sched_barrier(0);
    tile_mfma(lds + ((NKS_ - 2) % 3) * 8192, wrow, wcol, lr, lq, acc);
    // t = NKS_-1: drain
    asm volatile("s_waitcnt vmcnt(0)" ::: "memory");
    __builtin_amdgcn_s_barrier();
    __builtin_amdgcn_sched_barrier(0);
    tile_mfma(lds + ((NKS_ - 1) % 3) * 8192, wrow, wcol, lr, lq, acc);
}

// chunked XCD swizzle (nwg % 8 == 0), then col-fastest decode
__device__ __forceinline__ void tile_decode(int nwg, int ncol, int& rowt, int& colt) {
    int bid = blockIdx.x;
    int cpx = nwg >> 3;
    int swz = (bid & 7) * cpx + (bid >> 3);
    colt = swz % ncol;
    rowt = swz / ncol;
}

// ---------------------------------------------------------------------------
// H = gelu(Xb @ E1^T + b) -> bf16     grid: 512 blocks (2 cols x 256 rows)
// ---------------------------------------------------------------------------
__global__ __launch_bounds__(256, 3)
void gemm_e1_mfma(const unsigned short* __restrict__ Xb,
                  const unsigned short* __restrict__ Wb,
                  const float* __restrict__ bias,
                  unsigned short* __restrict__ H) {
    __shared__ unsigned short lds[3 * 8192];
    const int t = threadIdx.x, l = t & 63, w = t >> 6;
    int rowt, colt;
    tile_decode(512, 2, rowt, colt);
    const int row0 = rowt * 128, col0 = colt * 128;
    const int lr = l & 15, lq = l >> 4;
    const int wrow = (w >> 1) * 64, wcol = (w & 1) * 64;
    f32x4 acc[4][4] = {};
    kloop3(Xb, Wb, row0, col0, lds, w, l, acc);
#pragma unroll
    for (int m = 0; m < 4; m++)
#pragma unroll
        for (int n = 0; n < 4; n++) {
            int col = col0 + wcol + n * 16 + lr;
            float bc = bias[col];
#pragma unroll
            for (int r = 0; r < 4; r++) {
                int row = row0 + wrow + m * 16 + lq * 4 + r;
                H[(size_t)row * DB_ + col] = f2bf(gelu_exact(acc[m][n][r] + bc));
            }
        }
}

// ---------------------------------------------------------------------------
// Fused: gate = sigmoid(Xb@G^T+Gb) (held packed in regs), then
//        out = x32 + gelu(Sb@C^T) * gate.     grid: 1536 (6 cols x 256 rows)
// ---------------------------------------------------------------------------
__global__ __launch_bounds__(256, 3)
void gemm_fused_out(const unsigned short* __restrict__ Xb,
                    const unsigned short* __restrict__ Gwb,
                    const unsigned short* __restrict__ Sb,
                    const unsigned short* __restrict__ Cwb,
                    const float* __restrict__ Gbias,
                    const float* __restrict__ X32,
                    float* __restrict__ out) {
    __shared__ unsigned short lds[3 * 8192];
    const int t = threadIdx.x, l = t & 63, w = t >> 6;
    int rowt, colt;
    tile_decode(1536, 6, rowt, colt);
    const int row0 = rowt * 128, col0 = colt * 128;
    const int lr = l & 15, lq = l >> 4;
    const int wrow = (w >> 1) * 64, wcol = (w & 1) * 64;

    f32x4 acc[4][4] = {};
    kloop3(Xb, Gwb, row0, col0, lds, w, l, acc);

    // pack gate as bf16 pairs (32 VGPRs), reuse acc for the C GEMM
    unsigned int gp[4][4][2];
#pragma unroll
    for (int m = 0; m < 4; m++)
#pragma unroll
        for (int n = 0; n < 4; n++) {
            float gb = Gbias[col0 + wcol + n * 16 + lr];
            gp[m][n][0] = (unsigned)f2bf(sigmoidf_(acc[m][n][0] + gb))
                        | ((unsigned)f2bf(sigmoidf_(acc[m][n][1] + gb)) << 16);
            gp[m][n][1] = (unsigned)f2bf(sigmoidf_(acc[m][n][2] + gb))
                        | ((unsigned)f2bf(sigmoidf_(acc[m][n][3] + gb)) << 16);
            acc[m][n] = (f32x4){0.f, 0.f, 0.f, 0.f};
        }

    kloop3(Sb, Cwb, row0, col0, lds, w, l, acc);

#pragma unroll
    for (int m = 0; m < 4; m++)
#pragma unroll
        for (int n = 0; n < 4; n++) {
            int col = col0 + wcol + n * 16 + lr;
#pragma unroll
            for (int r = 0; r < 4; r++) {
                int row = row0 + wrow + m * 16 + lq * 4 + r;
                size_t o = (size_t)row * D_ + col;
                float g = bf2f((unsigned short)(gp[m][n][r >> 1] >> ((r & 1) * 16)));
                out[o] = X32[o] + gelu_exact(acc[m][n][r]) * g;
            }
        }
}

// ---------------------------------------------------------------------------
// Z = Xb @ V^T : (N x 768)(16 x 768)^T -> N x 16 fp32.
// One wave = 16 tokens; block = 4 waves = 64 tokens; grid 512.
// ---------------------------------------------------------------------------
__global__ __launch_bounds__(256)
void z_mfma(const unsigned short* __restrict__ Xb,
            const unsigned short* __restrict__ Vb,
            float* __restrict__ Z) {
    const int t = threadIdx.x, l = t & 63, w = t >> 6;
    const int lr = l & 15, lq = l >> 4;
    const int tok0 = (blockIdx.x * 4 + w) * 16;
    f32x4 acc = {};
#pragma unroll
    for (int k0 = 0; k0 < D_; k0 += 32) {
        bf16x8 a = *(const bf16x8*)&Xb[(size_t)(tok0 + lr) * D_ + k0 + lq * 8];
        bf16x8 b = *(const bf16x8*)&Vb[(size_t)lr * D_ + k0 + lq * 8];
        acc = __builtin_amdgcn_mfma_f32_16x16x32_bf16(a, b, acc, 0, 0, 0);
    }
#pragma unroll
    for (int rr = 0; rr < 4; rr++)
        Z[(size_t)(tok0 + lq * 4 + rr) * R_ + lr] = acc[rr];
}

// ---------------------------------------------------------------------------
// alpha[tok][c] = sigmoid(sum_e h[tok][e]*E2w[c][e] + E2b[c])
// ---------------------------------------------------------------------------
__global__ __launch_bounds__(256)
void alpha_kernel(const unsigned short* __restrict__ H,
                  const float* __restrict__ E2w, const float* __restrict__ E2b,
                  float* __restrict__ alpha) {
    const int t = threadIdx.x, l = t & 63, w = t >> 6;
    const size_t tok = blockIdx.x * 4 + w;
    ushort4 hv = *(const ushort4*)&H[tok * DB_ + l * 4];
    float h0 = bf2f(hv.x), h1 = bf2f(hv.y), h2 = bf2f(hv.z), h3 = bf2f(hv.w);
    float p[3];
#pragma unroll
    for (int c = 0; c < 3; c++) {
        float4 e = *(const float4*)&E2w[c * DB_ + l * 4];
        p[c] = h0 * e.x + h1 * e.y + h2 * e.z + h3 * e.w;
#pragma unroll
        for (int m = 32; m >= 1; m >>= 1) p[c] += __shfl_xor(p[c], m);
    }
    if (l == 0) {
        alpha[tok * 3 + 0] = sigmoidf_(p[0] + E2b[0]);
        alpha[tok * 3 + 1] = sigmoidf_(p[1] + E2b[1]);
        alpha[tok * 3 + 2] = sigmoidf_(p[2] + E2b[2]);
    }
}

// ---------------------------------------------------------------------------
// Scan with on-the-fly lam/bu recompute.
// ---------------------------------------------------------------------------
__device__ __forceinline__ void load_chunk_lds(const float* __restrict__ Z,
                                               const float* __restrict__ alpha,
                                               int tok0, int t,
                                               float* Zs, float* als) {
#pragma unroll
    for (int i = t; i < L_ * R_ / 4; i += 192)
        *(float4*)&Zs[i * 4] = *(const float4*)&Z[(size_t)tok0 * R_ + i * 4];
    als[t] = alpha[(size_t)tok0 * 3 + t];   // exactly 192 = 64*3
}

__device__ __forceinline__ float dot16(const float* zrow, const float4* u) {
    float4 z0 = *(const float4*)&zrow[0],  z1 = *(const float4*)&zrow[4];
    float4 z2 = *(const float4*)&zrow[8],  z3 = *(const float4*)&zrow[12];
    return z0.x*u[0].x + z0.y*u[0].y + z0.z*u[0].z + z0.w*u[0].w
         + z1.x*u[1].x + z1.y*u[1].y + z1.z*u[1].z + z1.w*u[1].w
         + z2.x*u[2].x + z2.y*u[2].y + z2.z*u[2].z + z2.w*u[2].w
         + z3.x*u[3].x + z3.y*u[3].y + z3.z*u[3].z + z3.w*u[3].w;
}

__global__ __launch_bounds__(192)
void scan_pass1(const float* __restrict__ Z, const float* __restrict__ alpha,
                const float* __restrict__ Uw, const float* __restrict__ a_base,
                const float* __restrict__ tanhd,
                float* __restrict__ Aagg, float* __restrict__ Send) {
    __shared__ float Zs[L_ * R_];
    __shared__ float als[L_ * 3];
    const int t = threadIdx.x;
    const int c = blockIdx.x & (NC_ - 1);
    const int b = blockIdx.x >> 6;
    const int tok0 = b * T_ + c * L_;
    const int d0 = t * 4;
    const int buck = d0 >> 8;
    load_chunk_lds(Z, alpha, tok0, t, Zs, als);

    float4 u[4][4];
#pragma unroll
    for (int j = 0; j < 4; j++)
#pragma unroll
        for (int q = 0; q < 4; q++)
            u[j][q] = *(const float4*)&Uw[(size_t)(d0 + j) * R_ + q * 4];
    float4 ab = *(const float4*)&a_base[d0];
    float4 td = *(const float4*)&tanhd[d0];
    float abv[4] = {ab.x, ab.y, ab.z, ab.w};
    float tdv[4] = {td.x, td.y, td.z, td.w};
    __syncthreads();

    float a[4] = {1.f, 1.f, 1.f, 1.f}, s[4] = {};
    for (int i = 0; i < L_; i++) {
        float av = als[i * 3 + buck];
#pragma unroll
        for (int j = 0; j < 4; j++) {
            float lam = sigmoidf_(fmaf(av, tdv[j], abv[j]));
            float bu  = dot16(&Zs[i * R_], u[j]);
            a[j] *= lam;
            s[j] = fmaf(lam, s[j], bu);
        }
    }
    size_t o = ((size_t)(b * NC_ + c)) * D_ + d0;
    *(float4*)&Aagg[o] = make_float4(a[0], a[1], a[2], a[3]);
    *(float4*)&Send[o] = make_float4(s[0], s[1], s[2], s[3]);
}

__global__ void scan_pass2(const float* __restrict__ Aagg, const float* __restrict__ Send,
                           float* __restrict__ Cin) {
    const int d = threadIdx.x;              // 768 threads
    const int b = blockIdx.x;               // 8 blocks
    float s = 0.f;
    for (int c = 0; c < NC_; c++) {
        size_t o = ((size_t)(b * NC_ + c)) * D_ + d;
        Cin[o] = s;
        s = fmaf(Aagg[o], s, Send[o]);
    }
}

__global__ __launch_bounds__(192)
void scan_pass3(const float* __restrict__ Z, const float* __restrict__ alpha,
                const float* __restrict__ Uw, const float* __restrict__ a_base,
                const float* __restrict__ tanhd, const float* __restrict__ Cin,
                unsigned short* __restrict__ Sout) {
    __shared__ float Zs[L_ * R_];
    __shared__ float als[L_ * 3];
    const int t = threadIdx.x;
    const int c = blockIdx.x & (NC_ - 1);
    const int b = blockIdx.x >> 6;
    const int tok0 = b * T_ + c * L_;
    const int d0 = t * 4;
    const int buck = d0 >> 8;
    load_chunk_lds(Z, alpha, tok0, t, Zs, als);

    float4 u[4][4];
#pragma unroll
    for (int j = 0; j < 4; j++)
#pragma unroll
        for (int q = 0; q < 4; q++)
            u[j][q] = *(const float4*)&Uw[(size_t)(d0 + j) * R_ + q * 4];
    float4 ab = *(const float4*)&a_base[d0];
    float4 td = *(const float4*)&tanhd[d0];
    float abv[4] = {ab.x, ab.y, ab.z, ab.w};
    float tdv[4] = {td.x, td.y, td.z, td.w};
    __syncthreads();

    size_t ci = ((size_t)(b * NC_ + c)) * D_ + d0;
    float4 c4 = *(const float4*)&Cin[ci];
    float s[4] = {c4.x, c4.y, c4.z, c4.w};
    for (int i = 0; i < L_; i++) {
        float av = als[i * 3 + buck];
#pragma unroll
        for (int j = 0; j < 4; j++) {
            float lam = sigmoidf_(fmaf(av, tdv[j], abv[j]));
            float bu  = dot16(&Zs[i * R_], u[j]);
            s[j] = fmaf(lam, s[j], bu);
        }
        *(ushort4*)&Sout[(size_t)(tok0 + i) * D_ + d0] =
            make_ushort4(f2bf(s[0]), f2bf(s[1]), f2bf(s[2]), f2bf(s[3]));
    }
}

// ---------------------------------------------------------------------------
// small conversion kernels
// ---------------------------------------------------------------------------
__global__ void cvt_bf16_vec(const float* __restrict__ in, unsigned short* __restrict__ out, int n4) {
    int i = blockIdx.x * 256 + threadIdx.x;
    if (i < n4) {
        float4 v = ((const float4*)in)[i];
        ((ushort4*)out)[i] = make_ushort4(f2bf(v.x), f2bf(v.y), f2bf(v.z), f2bf(v.w));
    }
}
__global__ void tanh_vec(const float* __restrict__ in, float* __restrict__ out, int n) {
    int i = blockIdx.x * 256 + threadIdx.x;
    if (i < n) out[i] = tanhf(in[i]);
}

// ---------------------------------------------------------------------------
extern "C" void kernel_launch(void* const* d_in, const int* in_sizes, int n_in,
                              void* d_out, int out_size, void* d_ws, size_t ws_size,
                              hipStream_t stream) {
    const float* x       = (const float*)d_in[0];
    const float* V_w     = (const float*)d_in[1];
    const float* U_w     = (const float*)d_in[2];
    const float* E1_w    = (const float*)d_in[3];
    const float* E1_b    = (const float*)d_in[4];
    const float* E2_w    = (const float*)d_in[5];
    const float* E2_b    = (const float*)d_in[6];
    const float* a_base  = (const float*)d_in[7];
    const float* a_delta = (const float*)d_in[8];
    const float* C_w     = (const float*)d_in[9];
    const float* G_w     = (const float*)d_in[10];
    const float* G_b     = (const float*)d_in[11];
    float* out = (float*)d_out;

    // workspace layout
    char* p = (char*)d_ws;
    float* Aagg  = (float*)p;           p += (size_t)B_ * NC_ * D_ * 4;
    float* Send  = (float*)p;           p += (size_t)B_ * NC_ * D_ * 4;
    float* Cin   = (float*)p;           p += (size_t)B_ * NC_ * D_ * 4;
    float* tanhd = (float*)p;           p += (size_t)D_ * 4;
    float* Z     = (float*)p;           p += (size_t)N_ * R_ * 4;
    float* alpha = (float*)p;           p += (size_t)N_ * 3 * 4;
    unsigned short* x_bf  = (unsigned short*)p; p += (size_t)N_ * D_ * 2;
    unsigned short* H_bf  = (unsigned short*)p; p += (size_t)N_ * DB_ * 2;
    unsigned short* S_bf  = (unsigned short*)p; p += (size_t)N_ * D_ * 2;
    unsigned short* E1_bf = (unsigned short*)p; p += (size_t)DB_ * D_ * 2;
    unsigned short* Cw_bf = (unsigned short*)p; p += (size_t)D_ * D_ * 2;
    unsigned short* Gw_bf = (unsigned short*)p; p += (size_t)D_ * D_ * 2;
    unsigned short* V_bf  = (unsigned short*)p; p += (size_t)R_ * D_ * 2;

    // conversions
    {
        int n4 = N_ * D_ / 4;
        cvt_bf16_vec<<<(n4 + 255) / 256, 256, 0, stream>>>(x, x_bf, n4);
        n4 = DB_ * D_ / 4;
        cvt_bf16_vec<<<(n4 + 255) / 256, 256, 0, stream>>>(E1_w, E1_bf, n4);
        n4 = D_ * D_ / 4;
        cvt_bf16_vec<<<(n4 + 255) / 256, 256, 0, stream>>>(C_w, Cw_bf, n4);
        cvt_bf16_vec<<<(n4 + 255) / 256, 256, 0, stream>>>(G_w, Gw_bf, n4);
        n4 = R_ * D_ / 4;
        cvt_bf16_vec<<<(n4 + 255) / 256, 256, 0, stream>>>(V_w, V_bf, n4);
        tanh_vec<<<3, 256, 0, stream>>>(a_delta, tanhd, D_);
    }

    gemm_e1_mfma<<<512, 256, 0, stream>>>(x_bf, E1_bf, E1_b, H_bf);
    alpha_kernel<<<N_ / 4, 256, 0, stream>>>(H_bf, E2_w, E2_b, alpha);
    z_mfma<<<N_ / 64, 256, 0, stream>>>(x_bf, V_bf, Z);

    scan_pass1<<<B_ * NC_, 192, 0, stream>>>(Z, alpha, U_w, a_base, tanhd, Aagg, Send);
    scan_pass2<<<B_,       D_,  0, stream>>>(Aagg, Send, Cin);
    scan_pass3<<<B_ * NC_, 192, 0, stream>>>(Z, alpha, U_w, a_base, tanhd, Cin, S_bf);

    gemm_fused_out<<<1536, 256, 0, stream>>>(x_bf, Gw_bf, S_bf, Cw_bf, G_b, x, out);
}

// Round 6
// 300.190 us; speedup vs baseline: 5.3484x; 1.1393x over previous
//
#include <hip/hip_runtime.h>
#include <hip/hip_bf16.h>
#include <math.h>

// Problem constants
#define B_   8
#define T_   4096
#define D_   768
#define R_   16
#define DB_  256
#define N_   (B_ * T_)      // 32768 tokens
#define NC_  64             // scan chunks per sequence
#define L_   (T_ / NC_)     // 64 steps per chunk
#define NKS_ (D_ / 32)      // 24 K-steps of 32

typedef __attribute__((ext_vector_type(8))) short bf16x8;
typedef __attribute__((ext_vector_type(4))) float f32x4;

__device__ __forceinline__ float gelu_exact(float x) {
    return 0.5f * x * (1.0f + erff(x * 0.70710678118654752f));
}
__device__ __forceinline__ float sigmoidf_(float x) {
    return 1.0f / (1.0f + expf(-x));
}
__device__ __forceinline__ float bf2f(unsigned short u) {
    return __uint_as_float(((unsigned)u) << 16);
}
__device__ __forceinline__ unsigned short f2bf(float f) {
    __hip_bfloat16 h = __float2bfloat16(f);   // RNE
    return *(unsigned short*)&h;
}
__device__ __forceinline__ bf16x8 pack8(float4 a, float4 b) {
    bf16x8 r;
    r[0] = (short)f2bf(a.x); r[1] = (short)f2bf(a.y);
    r[2] = (short)f2bf(a.z); r[3] = (short)f2bf(a.w);
    r[4] = (short)f2bf(b.x); r[5] = (short)f2bf(b.y);
    r[6] = (short)f2bf(b.z); r[7] = (short)f2bf(b.w);
    return r;
}

// async global->LDS, 16B per lane. LDS dest = wave-uniform base + lane*16.
__device__ __forceinline__ void gload16(const unsigned short* g, unsigned short* l) {
    __builtin_amdgcn_global_load_lds(
        (const __attribute__((address_space(1))) unsigned int*)(const void*)g,
        (__attribute__((address_space(3))) unsigned int*)(void*)l,
        16, 0, 0);
}

// ---------------------------------------------------------------------------
// Stage a 128x32 bf16 tile into LDS; swizzle the SOURCE quad, linear LDS dest
// (rule 21). 2 gloads per thread per tile -> 4 per K-tile (A+B).
// ---------------------------------------------------------------------------
__device__ __forceinline__ void stage_tile(const unsigned short* src, int ld,
                                           int row0, int k0,
                                           unsigned short* lds, int w, int l) {
#pragma unroll
    for (int j = 0; j < 2; ++j) {
        int i   = ((w * 2 + j) << 6) + l;   // 0..511 16B-chunks
        int row = i >> 2;
        int q   = i & 3;
        int qs  = q ^ ((row >> 1) & 3);
        const unsigned short* g = src + (size_t)(row0 + row) * ld + k0 + qs * 8;
        gload16(g, lds + ((w * 2 + j) << 9));
    }
}

// swizzled LDS fragment read: 8 bf16 for mfma_16x16x32 (bank-conflict-free)
__device__ __forceinline__ bf16x8 frag_read(const unsigned short* lds, int row, int lq) {
    int q = lq ^ ((row >> 1) & 3);
    return *(const bf16x8*)(lds + row * 32 + q * 8);
}

__device__ __forceinline__ void tile_mfma(const unsigned short* bc,
                                          int wrow, int wcol, int lr, int lq,
                                          f32x4 acc[4][4]) {
    bf16x8 a[4], b[4];
#pragma unroll
    for (int m = 0; m < 4; m++) a[m] = frag_read(bc, wrow + m * 16 + lr, lq);
#pragma unroll
    for (int n = 0; n < 4; n++) b[n] = frag_read(bc + 4096, wcol + n * 16 + lr, lq);
    __builtin_amdgcn_s_setprio(1);      // T5: favor the MFMA cluster
#pragma unroll
    for (int m = 0; m < 4; m++)
#pragma unroll
        for (int n = 0; n < 4; n++)
            acc[m][n] = __builtin_amdgcn_mfma_f32_16x16x32_bf16(a[m], b[n], acc[m][n], 0, 0, 0);
    __builtin_amdgcn_s_setprio(0);
}

// issue the 2-tile prologue for a K-loop (tiles 0 and 1 into buf0/buf1)
__device__ __forceinline__ void kloop_prologue(const unsigned short* __restrict__ A,
                                               const unsigned short* __restrict__ Bm,
                                               int row0, int col0,
                                               unsigned short* lds, int w, int l) {
    stage_tile(A,  D_, row0, 0,  lds,         w, l);
    stage_tile(Bm, D_, col0, 0,  lds + 4096,  w, l);
    stage_tile(A,  D_, row0, 32, lds + 8192,  w, l);
    stage_tile(Bm, D_, col0, 32, lds + 12288, w, l);
}

// ---------------------------------------------------------------------------
// 128x128-tile K-loop, 3-deep pipeline with counted vmcnt (never 0 in the
// main loop). Prologue may be issued earlier by the caller (overlap).
// ---------------------------------------------------------------------------
template <bool DO_PROLOGUE>
__device__ __forceinline__ void kloop3(const unsigned short* __restrict__ A,
                                       const unsigned short* __restrict__ Bm,
                                       int row0, int col0,
                                       unsigned short* lds,   // 3 * 8192 elems
                                       int w, int l, f32x4 acc[4][4]) {
    const int lr = l & 15, lq = l >> 4;
    const int wrow = (w >> 1) * 64, wcol = (w & 1) * 64;

    if (DO_PROLOGUE) kloop_prologue(A, Bm, row0, col0, lds, w, l);

#pragma unroll 3
    for (int t = 0; t < NKS_ - 2; ++t) {
        asm volatile("s_waitcnt vmcnt(4)" ::: "memory");
        __builtin_amdgcn_s_barrier();
        __builtin_amdgcn_sched_barrier(0);
        unsigned short* bn = lds + ((t + 2) % 3) * 8192;
        stage_tile(A,  D_, row0, (t + 2) * 32, bn,        w, l);
        stage_tile(Bm, D_, col0, (t + 2) * 32, bn + 4096, w, l);
        tile_mfma(lds + (t % 3) * 8192, wrow, wcol, lr, lq, acc);
    }
    // t = NKS_-2: tiles NKS_-2 (oldest 4) + NKS_-1 in flight
    asm volatile("s_waitcnt vmcnt(4)" ::: "memory");
    __builtin_amdgcn_s_barrier();
    __builtin_amdgcn_sched_barrier(0);
    tile_mfma(lds + ((NKS_ - 2) % 3) * 8192, wrow, wcol, lr, lq, acc);
    // t = NKS_-1: drain
    asm volatile("s_waitcnt vmcnt(0)" ::: "memory");
    __builtin_amdgcn_s_barrier();
    __builtin_amdgcn_sched_barrier(0);
    tile_mfma(lds + ((NKS_ - 1) % 3) * 8192, wrow, wcol, lr, lq, acc);
}

// chunked XCD swizzle (nwg % 8 == 0), then col-fastest decode
__device__ __forceinline__ void tile_decode(int nwg, int ncol, int& rowt, int& colt) {
    int bid = blockIdx.x;
    int cpx = nwg >> 3;
    int swz = (bid & 7) * cpx + (bid >> 3);
    colt = swz % ncol;
    rowt = swz / ncol;
}

// ---------------------------------------------------------------------------
// H = gelu(Xb @ E1^T + b) -> bf16     grid: 512 blocks (2 cols x 256 rows)
// ---------------------------------------------------------------------------
__global__ __launch_bounds__(256, 3)
void gemm_e1_mfma(const unsigned short* __restrict__ Xb,
                  const unsigned short* __restrict__ Wb,
                  const float* __restrict__ bias,
                  unsigned short* __restrict__ H) {
    __shared__ unsigned short lds[3 * 8192];
    const int t = threadIdx.x, l = t & 63, w = t >> 6;
    int rowt, colt;
    tile_decode(512, 2, rowt, colt);
    const int row0 = rowt * 128, col0 = colt * 128;
    const int lr = l & 15, lq = l >> 4;
    const int wrow = (w >> 1) * 64, wcol = (w & 1) * 64;
    f32x4 acc[4][4] = {};
    kloop3<true>(Xb, Wb, row0, col0, lds, w, l, acc);
#pragma unroll
    for (int m = 0; m < 4; m++)
#pragma unroll
        for (int n = 0; n < 4; n++) {
            int col = col0 + wcol + n * 16 + lr;
            float bc = bias[col];
#pragma unroll
            for (int r = 0; r < 4; r++) {
                int row = row0 + wrow + m * 16 + lq * 4 + r;
                H[(size_t)row * DB_ + col] = f2bf(gelu_exact(acc[m][n][r] + bc));
            }
        }
}

// ---------------------------------------------------------------------------
// Fused: gate = sigmoid(Xb@G^T+Gb) (packed in regs), then
//        out = x_bf + gelu(Sb@C^T) * gate.   grid: 1536 (6 cols x 256 rows)
// ---------------------------------------------------------------------------
__global__ __launch_bounds__(256, 3)
void gemm_fused_out(const unsigned short* __restrict__ Xb,
                    const unsigned short* __restrict__ Gwb,
                    const unsigned short* __restrict__ Sb,
                    const unsigned short* __restrict__ Cwb,
                    const float* __restrict__ Gbias,
                    float* __restrict__ out) {
    __shared__ unsigned short lds[3 * 8192];
    const int t = threadIdx.x, l = t & 63, w = t >> 6;
    int rowt, colt;
    tile_decode(1536, 6, rowt, colt);
    const int row0 = rowt * 128, col0 = colt * 128;
    const int lr = l & 15, lq = l >> 4;
    const int wrow = (w >> 1) * 64, wcol = (w & 1) * 64;

    // hoist Gbias so the pack below is pure VALU (keeps vmcnt stream clean)
    float gb[4];
#pragma unroll
    for (int n = 0; n < 4; n++) gb[n] = Gbias[col0 + wcol + n * 16 + lr];

    f32x4 acc[4][4] = {};
    kloop3<true>(Xb, Gwb, row0, col0, lds, w, l, acc);

    // issue kloop-C prologue NOW: its HBM latency hides under the gate pack.
    // Safe: buf0/buf1 readers all passed the final kloop-G barriers.
    kloop_prologue(Sb, Cwb, row0, col0, lds, w, l);

    // pack gate as bf16 pairs (32 VGPRs), reuse acc for the C GEMM
    unsigned int gp[4][4][2];
#pragma unroll
    for (int m = 0; m < 4; m++)
#pragma unroll
        for (int n = 0; n < 4; n++) {
            gp[m][n][0] = (unsigned)f2bf(sigmoidf_(acc[m][n][0] + gb[n]))
                        | ((unsigned)f2bf(sigmoidf_(acc[m][n][1] + gb[n])) << 16);
            gp[m][n][1] = (unsigned)f2bf(sigmoidf_(acc[m][n][2] + gb[n]))
                        | ((unsigned)f2bf(sigmoidf_(acc[m][n][3] + gb[n])) << 16);
            acc[m][n] = (f32x4){0.f, 0.f, 0.f, 0.f};
        }

    kloop3<false>(Sb, Cwb, row0, col0, lds, w, l, acc);

#pragma unroll
    for (int m = 0; m < 4; m++)
#pragma unroll
        for (int n = 0; n < 4; n++) {
            int col = col0 + wcol + n * 16 + lr;
#pragma unroll
            for (int r = 0; r < 4; r++) {
                int row = row0 + wrow + m * 16 + lq * 4 + r;
                size_t o = (size_t)row * D_ + col;
                float g = bf2f((unsigned short)(gp[m][n][r >> 1] >> ((r & 1) * 16)));
                out[o] = bf2f(Xb[o]) + gelu_exact(acc[m][n][r]) * g;
            }
        }
}

// ---------------------------------------------------------------------------
// Fused cvt + Z: x_bf = bf16(x);  Z = x_bf @ V^T (V converted on the fly).
// One wave = 16 tokens; block = 4 waves = 64 tokens; grid 512.
// ---------------------------------------------------------------------------
__global__ __launch_bounds__(256)
void cvtz_kernel(const float* __restrict__ X, const float* __restrict__ Vw,
                 unsigned short* __restrict__ Xb, float* __restrict__ Z) {
    const int t = threadIdx.x, l = t & 63, w = t >> 6;
    const int lr = l & 15, lq = l >> 4;
    const int tok0 = (blockIdx.x * 4 + w) * 16;
    const float* xrow = X  + (size_t)(tok0 + lr) * D_;
    const float* vrow = Vw + (size_t)lr * D_;
    f32x4 acc = {};
#pragma unroll 4
    for (int k0 = 0; k0 < D_; k0 += 32) {
        int k = k0 + lq * 8;
        float4 xa = *(const float4*)&xrow[k];
        float4 xb = *(const float4*)&xrow[k + 4];
        float4 va = *(const float4*)&vrow[k];
        float4 vb = *(const float4*)&vrow[k + 4];
        bf16x8 xf = pack8(xa, xb);
        bf16x8 vf = pack8(va, vb);
        *(bf16x8*)&Xb[(size_t)(tok0 + lr) * D_ + k] = xf;
        acc = __builtin_amdgcn_mfma_f32_16x16x32_bf16(xf, vf, acc, 0, 0, 0);
    }
    // D layout: col(=r) = lane&15, row(=token) = (lane>>4)*4 + reg
#pragma unroll
    for (int rr = 0; rr < 4; rr++)
        Z[(size_t)(tok0 + lq * 4 + rr) * R_ + lr] = acc[rr];
}

// ---------------------------------------------------------------------------
// alpha[tok][c] = sigmoid(sum_e h[tok][e]*E2w[c][e] + E2b[c])
// ---------------------------------------------------------------------------
__global__ __launch_bounds__(256)
void alpha_kernel(const unsigned short* __restrict__ H,
                  const float* __restrict__ E2w, const float* __restrict__ E2b,
                  float* __restrict__ alpha) {
    const int t = threadIdx.x, l = t & 63, w = t >> 6;
    const size_t tok = blockIdx.x * 4 + w;
    ushort4 hv = *(const ushort4*)&H[tok * DB_ + l * 4];
    float h0 = bf2f(hv.x), h1 = bf2f(hv.y), h2 = bf2f(hv.z), h3 = bf2f(hv.w);
    float p[3];
#pragma unroll
    for (int c = 0; c < 3; c++) {
        float4 e = *(const float4*)&E2w[c * DB_ + l * 4];
        p[c] = h0 * e.x + h1 * e.y + h2 * e.z + h3 * e.w;
#pragma unroll
        for (int m = 32; m >= 1; m >>= 1) p[c] += __shfl_xor(p[c], m);
    }
    if (l == 0) {
        alpha[tok * 3 + 0] = sigmoidf_(p[0] + E2b[0]);
        alpha[tok * 3 + 1] = sigmoidf_(p[1] + E2b[1]);
        alpha[tok * 3 + 2] = sigmoidf_(p[2] + E2b[2]);
    }
}

// ---------------------------------------------------------------------------
// Scan with on-the-fly lam/bu recompute.
// ---------------------------------------------------------------------------
__device__ __forceinline__ void load_chunk_lds(const float* __restrict__ Z,
                                               const float* __restrict__ alpha,
                                               int tok0, int t,
                                               float* Zs, float* als) {
#pragma unroll
    for (int i = t; i < L_ * R_ / 4; i += 192)
        *(float4*)&Zs[i * 4] = *(const float4*)&Z[(size_t)tok0 * R_ + i * 4];
    als[t] = alpha[(size_t)tok0 * 3 + t];   // exactly 192 = 64*3
}

__device__ __forceinline__ float dot16(const float* zrow, const float4* u) {
    float4 z0 = *(const float4*)&zrow[0],  z1 = *(const float4*)&zrow[4];
    float4 z2 = *(const float4*)&zrow[8],  z3 = *(const float4*)&zrow[12];
    return z0.x*u[0].x + z0.y*u[0].y + z0.z*u[0].z + z0.w*u[0].w
         + z1.x*u[1].x + z1.y*u[1].y + z1.z*u[1].z + z1.w*u[1].w
         + z2.x*u[2].x + z2.y*u[2].y + z2.z*u[2].z + z2.w*u[2].w
         + z3.x*u[3].x + z3.y*u[3].y + z3.z*u[3].z + z3.w*u[3].w;
}

__global__ __launch_bounds__(192)
void scan_pass1(const float* __restrict__ Z, const float* __restrict__ alpha,
                const float* __restrict__ Uw, const float* __restrict__ a_base,
                const float* __restrict__ tanhd,
                float* __restrict__ Aagg, float* __restrict__ Send) {
    __shared__ float Zs[L_ * R_];
    __shared__ float als[L_ * 3];
    const int t = threadIdx.x;
    const int c = blockIdx.x & (NC_ - 1);
    const int b = blockIdx.x >> 6;
    const int tok0 = b * T_ + c * L_;
    const int d0 = t * 4;
    const int buck = d0 >> 8;
    load_chunk_lds(Z, alpha, tok0, t, Zs, als);

    float4 u[4][4];
#pragma unroll
    for (int j = 0; j < 4; j++)
#pragma unroll
        for (int q = 0; q < 4; q++)
            u[j][q] = *(const float4*)&Uw[(size_t)(d0 + j) * R_ + q * 4];
    float4 ab = *(const float4*)&a_base[d0];
    float4 td = *(const float4*)&tanhd[d0];
    float abv[4] = {ab.x, ab.y, ab.z, ab.w};
    float tdv[4] = {td.x, td.y, td.z, td.w};
    __syncthreads();

    float a[4] = {1.f, 1.f, 1.f, 1.f}, s[4] = {};
    for (int i = 0; i < L_; i++) {
        float av = als[i * 3 + buck];
#pragma unroll
        for (int j = 0; j < 4; j++) {
            float lam = sigmoidf_(fmaf(av, tdv[j], abv[j]));
            float bu  = dot16(&Zs[i * R_], u[j]);
            a[j] *= lam;
            s[j] = fmaf(lam, s[j], bu);
        }
    }
    size_t o = ((size_t)(b * NC_ + c)) * D_ + d0;
    *(float4*)&Aagg[o] = make_float4(a[0], a[1], a[2], a[3]);
    *(float4*)&Send[o] = make_float4(s[0], s[1], s[2], s[3]);
}

__global__ void scan_pass2(const float* __restrict__ Aagg, const float* __restrict__ Send,
                           float* __restrict__ Cin) {
    const int d = threadIdx.x;              // 768 threads
    const int b = blockIdx.x;               // 8 blocks
    float s = 0.f;
    for (int c = 0; c < NC_; c++) {
        size_t o = ((size_t)(b * NC_ + c)) * D_ + d;
        Cin[o] = s;
        s = fmaf(Aagg[o], s, Send[o]);
    }
}

__global__ __launch_bounds__(192)
void scan_pass3(const float* __restrict__ Z, const float* __restrict__ alpha,
                const float* __restrict__ Uw, const float* __restrict__ a_base,
                const float* __restrict__ tanhd, const float* __restrict__ Cin,
                unsigned short* __restrict__ Sout) {
    __shared__ float Zs[L_ * R_];
    __shared__ float als[L_ * 3];
    const int t = threadIdx.x;
    const int c = blockIdx.x & (NC_ - 1);
    const int b = blockIdx.x >> 6;
    const int tok0 = b * T_ + c * L_;
    const int d0 = t * 4;
    const int buck = d0 >> 8;
    load_chunk_lds(Z, alpha, tok0, t, Zs, als);

    float4 u[4][4];
#pragma unroll
    for (int j = 0; j < 4; j++)
#pragma unroll
        for (int q = 0; q < 4; q++)
            u[j][q] = *(const float4*)&Uw[(size_t)(d0 + j) * R_ + q * 4];
    float4 ab = *(const float4*)&a_base[d0];
    float4 td = *(const float4*)&tanhd[d0];
    float abv[4] = {ab.x, ab.y, ab.z, ab.w};
    float tdv[4] = {td.x, td.y, td.z, td.w};
    __syncthreads();

    size_t ci = ((size_t)(b * NC_ + c)) * D_ + d0;
    float4 c4 = *(const float4*)&Cin[ci];
    float s[4] = {c4.x, c4.y, c4.z, c4.w};
    for (int i = 0; i < L_; i++) {
        float av = als[i * 3 + buck];
#pragma unroll
        for (int j = 0; j < 4; j++) {
            float lam = sigmoidf_(fmaf(av, tdv[j], abv[j]));
            float bu  = dot16(&Zs[i * R_], u[j]);
            s[j] = fmaf(lam, s[j], bu);
        }
        *(ushort4*)&Sout[(size_t)(tok0 + i) * D_ + d0] =
            make_ushort4(f2bf(s[0]), f2bf(s[1]), f2bf(s[2]), f2bf(s[3]));
    }
}

// ---------------------------------------------------------------------------
// small conversion kernels
// ---------------------------------------------------------------------------
__global__ void cvt_bf16_vec(const float* __restrict__ in, unsigned short* __restrict__ out, int n4) {
    int i = blockIdx.x * 256 + threadIdx.x;
    if (i < n4) {
        float4 v = ((const float4*)in)[i];
        ((ushort4*)out)[i] = make_ushort4(f2bf(v.x), f2bf(v.y), f2bf(v.z), f2bf(v.w));
    }
}
__global__ void tanh_vec(const float* __restrict__ in, float* __restrict__ out, int n) {
    int i = blockIdx.x * 256 + threadIdx.x;
    if (i < n) out[i] = tanhf(in[i]);
}

// ---------------------------------------------------------------------------
extern "C" void kernel_launch(void* const* d_in, const int* in_sizes, int n_in,
                              void* d_out, int out_size, void* d_ws, size_t ws_size,
                              hipStream_t stream) {
    const float* x       = (const float*)d_in[0];
    const float* V_w     = (const float*)d_in[1];
    const float* U_w     = (const float*)d_in[2];
    const float* E1_w    = (const float*)d_in[3];
    const float* E1_b    = (const float*)d_in[4];
    const float* E2_w    = (const float*)d_in[5];
    const float* E2_b    = (const float*)d_in[6];
    const float* a_base  = (const float*)d_in[7];
    const float* a_delta = (const float*)d_in[8];
    const float* C_w     = (const float*)d_in[9];
    const float* G_w     = (const float*)d_in[10];
    const float* G_b     = (const float*)d_in[11];
    float* out = (float*)d_out;

    // workspace layout
    char* p = (char*)d_ws;
    float* Aagg  = (float*)p;           p += (size_t)B_ * NC_ * D_ * 4;
    float* Send  = (float*)p;           p += (size_t)B_ * NC_ * D_ * 4;
    float* Cin   = (float*)p;           p += (size_t)B_ * NC_ * D_ * 4;
    float* tanhd = (float*)p;           p += (size_t)D_ * 4;
    float* Z     = (float*)p;           p += (size_t)N_ * R_ * 4;
    float* alpha = (float*)p;           p += (size_t)N_ * 3 * 4;
    unsigned short* x_bf  = (unsigned short*)p; p += (size_t)N_ * D_ * 2;
    unsigned short* H_bf  = (unsigned short*)p; p += (size_t)N_ * DB_ * 2;
    unsigned short* S_bf  = (unsigned short*)p; p += (size_t)N_ * D_ * 2;
    unsigned short* E1_bf = (unsigned short*)p; p += (size_t)DB_ * D_ * 2;
    unsigned short* Cw_bf = (unsigned short*)p; p += (size_t)D_ * D_ * 2;
    unsigned short* Gw_bf = (unsigned short*)p; p += (size_t)D_ * D_ * 2;

    // weight conversions + small precompute
    {
        int n4 = DB_ * D_ / 4;
        cvt_bf16_vec<<<(n4 + 255) / 256, 256, 0, stream>>>(E1_w, E1_bf, n4);
        n4 = D_ * D_ / 4;
        cvt_bf16_vec<<<(n4 + 255) / 256, 256, 0, stream>>>(C_w, Cw_bf, n4);
        cvt_bf16_vec<<<(n4 + 255) / 256, 256, 0, stream>>>(G_w, Gw_bf, n4);
        tanh_vec<<<3, 256, 0, stream>>>(a_delta, tanhd, D_);
    }

    // x -> bf16 and Z = x@V^T in one pass
    cvtz_kernel<<<N_ / 64, 256, 0, stream>>>(x, V_w, x_bf, Z);

    gemm_e1_mfma<<<512, 256, 0, stream>>>(x_bf, E1_bf, E1_b, H_bf);
    alpha_kernel<<<N_ / 4, 256, 0, stream>>>(H_bf, E2_w, E2_b, alpha);

    scan_pass1<<<B_ * NC_, 192, 0, stream>>>(Z, alpha, U_w, a_base, tanhd, Aagg, Send);
    scan_pass2<<<B_,       D_,  0, stream>>>(Aagg, Send, Cin);
    scan_pass3<<<B_ * NC_, 192, 0, stream>>>(Z, alpha, U_w, a_base, tanhd, Cin, S_bf);

    gemm_fused_out<<<1536, 256, 0, stream>>>(x_bf, Gw_bf, S_bf, Cw_bf, G_b, out);
}